// Round 1
// 232.963 us; speedup vs baseline: 1.0270x; 1.0270x over previous
//
#include <hip/hip_runtime.h>
#include <cstdint>
#include <cstddef>

typedef unsigned short u16;
typedef unsigned char u8;
typedef __attribute__((ext_vector_type(8))) u16 u16x8;
typedef __attribute__((ext_vector_type(8))) __bf16 bf16x8;
typedef __attribute__((ext_vector_type(4))) float f32x4;
typedef __attribute__((ext_vector_type(16))) float f32x16;
typedef __attribute__((ext_vector_type(4))) int i32x4;
typedef __attribute__((ext_vector_type(8))) int i32x8;

__device__ __forceinline__ u16 f2bf(float f) {
  unsigned u = __builtin_bit_cast(unsigned, f);
  return (u16)((u + 0x7FFFu + ((u >> 16) & 1u)) >> 16);
}
__device__ __forceinline__ float bf2f(u16 h) {
  return __builtin_bit_cast(float, (unsigned)h << 16);
}
__device__ __forceinline__ u8 f2fp8(float f) {
  return (u8)(__builtin_amdgcn_cvt_pk_fp8_f32(f, 0.f, 0, false) & 0xFF);
}
__device__ __forceinline__ f32x4 mfma16(u16x8 a, u16x8 b, f32x4 c) {
  return __builtin_amdgcn_mfma_f32_16x16x32_bf16(
      __builtin_bit_cast(bf16x8, a), __builtin_bit_cast(bf16x8, b), c, 0, 0, 0);
}
__device__ __forceinline__ void load_lds16(const void* g, void* l) {
  __builtin_amdgcn_global_load_lds(
      (const __attribute__((address_space(1))) void*)g,
      (__attribute__((address_space(3))) void*)l, 16, 0, 0);
}

// ---------------- all 4 weight transposes fused: dst[n][k] = fp8(src[k][n]), zero-padded
__global__ __launch_bounds__(256) void k_trcvt_all(
    const float* __restrict__ W1, const float* __restrict__ projW,
    const float* __restrict__ mlpW, const float* __restrict__ W2,
    u8* __restrict__ W1t, u8* __restrict__ pWt, u8* __restrict__ mWt,
    u8* __restrict__ W2t) {
  __shared__ float t[32][33];
  const int L = blockIdx.x;
  const float* src;
  u8* dst;
  int R, C, dR, dC, bx, by;
  if (L < 3840) {
    src = W1; dst = W1t; R = 1024; C = 3788; dR = 1024; dC = 3840;
    bx = L % 120; by = L / 120;
  } else if (L < 4864) {
    int tq = L - 3840;
    src = projW; dst = pWt; R = 1024; C = 1024; dR = 1024; dC = 1024;
    bx = tq & 31; by = tq >> 5;
  } else if (L < 5632) {
    int tq = L - 4864;
    src = mlpW; dst = mWt; R = 716; C = 1024; dR = 768; dC = 1024;
    bx = tq & 31; by = tq >> 5;
  } else {
    int tq = L - 5632;
    src = W2; dst = W2t; R = 2048; C = 1024; dR = 2048; dC = 1024;
    bx = tq & 31; by = tq >> 5;
  }
  const int n0 = bx * 32, k0 = by * 32;
  const int tx = threadIdx.x & 31, ty = threadIdx.x >> 5;
#pragma unroll
  for (int j = 0; j < 4; ++j) {
    int kk = k0 + ty + 8 * j, nn = n0 + tx;
    float v = (kk < R && nn < C) ? src[(size_t)kk * C + nn] : 0.f;
    t[ty + 8 * j][tx] = v;
  }
  __syncthreads();
#pragma unroll
  for (int j = 0; j < 4; ++j) {
    int nn = n0 + ty + 8 * j, kk = k0 + tx;
    if (nn < dC && kk < dR) dst[(size_t)nn * dR + kk] = f2fp8(t[tx][ty + 8 * j]);
  }
}

// ---------------- V^T extraction from f1 (bf16): vtb[bh][d][n]
__global__ __launch_bounds__(256) void k_trvt(const u16* __restrict__ f1,
                                              u16* __restrict__ vtb) {
  __shared__ u16 t[32][33];
  const int z = blockIdx.z;
  const int b = z >> 4, h = z & 15;
  const int d0 = blockIdx.x * 32, n0 = blockIdx.y * 32;
  const int tx = threadIdx.x & 31, ty = threadIdx.x >> 5;
#pragma unroll
  for (int j = 0; j < 4; ++j)
    t[ty + 8 * j][tx] =
        f1[(size_t)(b * 1024 + n0 + ty + 8 * j) * 3840 + 2048 + h * 64 + d0 + tx];
  __syncthreads();
#pragma unroll
  for (int j = 0; j < 4; ++j)
    vtb[(size_t)z * 65536 + (size_t)(d0 + ty + 8 * j) * 1024 + n0 + tx] =
        t[tx][ty + 8 * j];
}

// ---------------- LayerNorm over DIM=1024, fp32 in -> fp8 out
__global__ __launch_bounds__(256) void k_lnx(const float* __restrict__ x,
                                             const float* __restrict__ g,
                                             const float* __restrict__ b,
                                             u8* __restrict__ out) {
  const int row = blockIdx.x, tid = threadIdx.x;
  float4 v = ((const float4*)(x + (size_t)row * 1024))[tid];
  float s = v.x + v.y + v.z + v.w;
  float ss = v.x * v.x + v.y * v.y + v.z * v.z + v.w * v.w;
#pragma unroll
  for (int off = 1; off < 64; off <<= 1) {
    s += __shfl_xor(s, off);
    ss += __shfl_xor(ss, off);
  }
  __shared__ float red[8];
  const int wid = tid >> 6, lane = tid & 63;
  if (lane == 0) { red[wid] = s; red[4 + wid] = ss; }
  __syncthreads();
  s = red[0] + red[1] + red[2] + red[3];
  ss = red[4] + red[5] + red[6] + red[7];
  const float mean = s * (1.f / 1024.f);
  const float var = ss * (1.f / 1024.f) - mean * mean;
  const float rstd = rsqrtf(var + 1e-5f);
  float4 gv = ((const float4*)g)[tid];
  float4 bv = ((const float4*)b)[tid];
  float y0 = (v.x - mean) * rstd * gv.x + bv.x;
  float y1 = (v.y - mean) * rstd * gv.y + bv.y;
  float y2 = (v.z - mean) * rstd * gv.z + bv.z;
  float y3 = (v.w - mean) * rstd * gv.w + bv.w;
  int pk = __builtin_amdgcn_cvt_pk_fp8_f32(y0, y1, 0, false);
  pk = __builtin_amdgcn_cvt_pk_fp8_f32(y2, y3, pk, true);
  ((int*)(out + (size_t)row * 1024))[tid] = pk;
}

// ---------------- MX-fp8 GEMM core 128x128 (GEMM1): 32x32x64 f8f6f4, unit scales.
__device__ __forceinline__ void gemm_fp8_core(const u8* __restrict__ A,
                                              const u8* __restrict__ B, int K,
                                              u8* Alds, u8* Blds,
                                              f32x16 (&acc)[2][2], int tid) {
  const int lane = tid & 63, wave = tid >> 6;
  const int h = lane >> 5, r32 = lane & 31;
  const int wrow = (wave >> 1) * 64, wcol = (wave & 1) * 64;
  const int srow0 = tid >> 2, spos = tid & 3;
  const int nk = K >> 6;
  for (int kt = 0; kt < nk; ++kt) {
#pragma unroll
    for (int p = 0; p < 2; ++p) {
      const int row = p * 64 + srow0;
      const int c = spos ^ ((row >> 1) & 3);
      const size_t go = (size_t)row * K + kt * 64 + c * 16;
      load_lds16(A + go, Alds + (p * 256 + tid) * 16);
      load_lds16(B + go, Blds + (p * 256 + tid) * 16);
    }
    __syncthreads();
    i32x8 af[2], bf[2];
#pragma unroll
    for (int t = 0; t < 2; ++t) {
      {
        const int row = wrow + t * 32 + r32;
        const int sw = (row >> 1) & 3;
        i32x4 lo = *(const i32x4*)(Alds + row * 64 + ((2 * h) ^ sw) * 16);
        i32x4 hi = *(const i32x4*)(Alds + row * 64 + ((2 * h + 1) ^ sw) * 16);
        i32x8 a;
        a[0] = lo[0]; a[1] = lo[1]; a[2] = lo[2]; a[3] = lo[3];
        a[4] = hi[0]; a[5] = hi[1]; a[6] = hi[2]; a[7] = hi[3];
        af[t] = a;
      }
      {
        const int row = wcol + t * 32 + r32;
        const int sw = (row >> 1) & 3;
        i32x4 lo = *(const i32x4*)(Blds + row * 64 + ((2 * h) ^ sw) * 16);
        i32x4 hi = *(const i32x4*)(Blds + row * 64 + ((2 * h + 1) ^ sw) * 16);
        i32x8 b8;
        b8[0] = lo[0]; b8[1] = lo[1]; b8[2] = lo[2]; b8[3] = lo[3];
        b8[4] = hi[0]; b8[5] = hi[1]; b8[6] = hi[2]; b8[7] = hi[3];
        bf[t] = b8;
      }
    }
#pragma unroll
    for (int i = 0; i < 2; ++i)
#pragma unroll
      for (int j = 0; j < 2; ++j)
        acc[i][j] = __builtin_amdgcn_mfma_scale_f32_32x32x64_f8f6f4(
            af[i], bf[j], acc[i][j], 0, 0, 0, 0x7F7F7F7F, 0, 0x7F7F7F7F);
    __syncthreads();
  }
}

// ---------------- MX-fp8 GEMM core 64(M)x128(N): more blocks/CU for small GEMMs
__device__ __forceinline__ void gemm_fp8_core64(const u8* __restrict__ A,
                                                const u8* __restrict__ B, int K,
                                                u8* Alds, u8* Blds,
                                                f32x16 (&acc)[2], int tid) {
  const int lane = tid & 63, wave = tid >> 6;
  const int h = lane >> 5, r32 = lane & 31;
  const int wrow = (wave >> 1) * 32, wcol = (wave & 1) * 64;
  const int nk = K >> 6;
  for (int kt = 0; kt < nk; ++kt) {
    {
      const int r = tid >> 2, pos = tid & 3;
      const int c = pos ^ ((r >> 1) & 3);
      load_lds16(A + (size_t)r * K + kt * 64 + c * 16, Alds + tid * 16);
    }
#pragma unroll
    for (int p = 0; p < 2; ++p) {
      const int s = tid + 256 * p;
      const int r = s >> 2, pos = s & 3;
      const int c = pos ^ ((r >> 1) & 3);
      load_lds16(B + (size_t)r * K + kt * 64 + c * 16, Blds + s * 16);
    }
    __syncthreads();
    i32x8 af, bf[2];
    {
      const int row = wrow + r32;
      const int sw = (row >> 1) & 3;
      i32x4 lo = *(const i32x4*)(Alds + row * 64 + ((2 * h) ^ sw) * 16);
      i32x4 hi = *(const i32x4*)(Alds + row * 64 + ((2 * h + 1) ^ sw) * 16);
      af[0] = lo[0]; af[1] = lo[1]; af[2] = lo[2]; af[3] = lo[3];
      af[4] = hi[0]; af[5] = hi[1]; af[6] = hi[2]; af[7] = hi[3];
    }
#pragma unroll
    for (int t = 0; t < 2; ++t) {
      const int row = wcol + t * 32 + r32;
      const int sw = (row >> 1) & 3;
      i32x4 lo = *(const i32x4*)(Blds + row * 64 + ((2 * h) ^ sw) * 16);
      i32x4 hi = *(const i32x4*)(Blds + row * 64 + ((2 * h + 1) ^ sw) * 16);
      i32x8 b8;
      b8[0] = lo[0]; b8[1] = lo[1]; b8[2] = lo[2]; b8[3] = lo[3];
      b8[4] = hi[0]; b8[5] = hi[1]; b8[6] = hi[2]; b8[7] = hi[3];
      bf[t] = b8;
    }
#pragma unroll
    for (int j = 0; j < 2; ++j)
      acc[j] = __builtin_amdgcn_mfma_scale_f32_32x32x64_f8f6f4(
          af, bf[j], acc[j], 0, 0, 0, 0x7F7F7F7F, 0, 0x7F7F7F7F);
    __syncthreads();
  }
}

// ---------------- GEMM1: f1[4096][3840] bf16 = nx8 @ W1t^T + b1
__global__ __launch_bounds__(256) void k_gemm1(const u8* __restrict__ nx8,
                                               const u8* __restrict__ W1t,
                                               u16* __restrict__ f1,
                                               const float* __restrict__ b1) {
  __shared__ __align__(16) u8 Alds[128 * 64];
  __shared__ __align__(16) u8 Blds[128 * 64];
  const int tid = threadIdx.x, bm = blockIdx.y, bn = blockIdx.x;
  f32x16 acc[2][2];
#pragma unroll
  for (int i = 0; i < 2; ++i)
#pragma unroll
    for (int j = 0; j < 2; ++j)
#pragma unroll
      for (int r = 0; r < 16; ++r) acc[i][j][r] = 0.f;
  gemm_fp8_core(nx8 + (size_t)bm * 128 * 1024, W1t + (size_t)bn * 128 * 1024, 1024,
                Alds, Blds, acc, tid);
  const int lane = tid & 63, wave = tid >> 6;
  const int h = lane >> 5, r32 = lane & 31;
  const int wrow = (wave >> 1) * 64, wcol = (wave & 1) * 64;
#pragma unroll
  for (int i = 0; i < 2; ++i)
#pragma unroll
    for (int j = 0; j < 2; ++j) {
      const int col = bn * 128 + wcol + j * 32 + r32;
      const float bs = (col < 3788) ? b1[col] : 0.f;
#pragma unroll
      for (int r = 0; r < 16; ++r) {
        const int row = bm * 128 + wrow + i * 32 + 4 * h + (r & 3) + 8 * (r >> 2);
        f1[(size_t)row * 3840 + col] = f2bf(acc[i][j][r] + bs);
      }
    }
}

// ---------------- proj + mlp fused (64-row tiles): comb[4096][2048] fp8
__global__ __launch_bounds__(256) void k_gemm_pm(
    const u8* __restrict__ xo, const u8* __restrict__ pWt,
    const u8* __restrict__ gel, const u8* __restrict__ mWt,
    u8* __restrict__ comb, const float* __restrict__ projb) {
  __shared__ __align__(16) u8 Alds[64 * 64];
  __shared__ __align__(16) u8 Blds[128 * 64];
  const int tid = threadIdx.x, bm = blockIdx.y, bnq = blockIdx.x;
  const u8* A;
  const u8* B;
  int K, colbase;
  const float* bias;
  if (bnq < 8) {
    A = xo + (size_t)bm * 64 * 1024;
    B = pWt + (size_t)bnq * 128 * 1024;
    K = 1024; colbase = bnq * 128; bias = projb;
  } else {
    A = gel + (size_t)bm * 64 * 768;
    B = mWt + (size_t)(bnq - 8) * 128 * 768;
    K = 768; colbase = 1024 + (bnq - 8) * 128; bias = nullptr;
  }
  f32x16 acc[2];
#pragma unroll
  for (int j = 0; j < 2; ++j)
#pragma unroll
    for (int r = 0; r < 16; ++r) acc[j][r] = 0.f;
  gemm_fp8_core64(A, B, K, Alds, Blds, acc, tid);
  const int lane = tid & 63, wave = tid >> 6;
  const int h = lane >> 5, r32 = lane & 31;
  const int wrow = (wave >> 1) * 32, wcol = (wave & 1) * 64;
#pragma unroll
  for (int j = 0; j < 2; ++j) {
    const int col = colbase + wcol + j * 32 + r32;
    // bias indexed by full column within projb (only the proj half has bias)
    const float bs = (bias != nullptr) ? bias[col] : 0.f;
#pragma unroll
    for (int r = 0; r < 16; ++r) {
      const int row = bm * 64 + wrow + 4 * h + (r & 3) + 8 * (r >> 2);
      comb[(size_t)row * 2048 + col] = f2fp8(acc[j][r] + bs);
    }
  }
}

// ---------------- final (64-row tiles): out = x + (comb @ W2t^T + b2) * ls_g
__global__ __launch_bounds__(256) void k_gemm_fin(const u8* __restrict__ comb,
                                                  const u8* __restrict__ W2t,
                                                  float* __restrict__ out,
                                                  const float* __restrict__ b2,
                                                  const float* __restrict__ x,
                                                  const float* __restrict__ lsg) {
  __shared__ __align__(16) u8 Alds[64 * 64];
  __shared__ __align__(16) u8 Blds[128 * 64];
  const int tid = threadIdx.x, bm = blockIdx.y, bn = blockIdx.x;
  f32x16 acc[2];
#pragma unroll
  for (int j = 0; j < 2; ++j)
#pragma unroll
    for (int r = 0; r < 16; ++r) acc[j][r] = 0.f;
  gemm_fp8_core64(comb + (size_t)bm * 64 * 2048, W2t + (size_t)bn * 128 * 2048, 2048,
                  Alds, Blds, acc, tid);
  const int lane = tid & 63, wave = tid >> 6;
  const int h = lane >> 5, r32 = lane & 31;
  const int wrow = (wave >> 1) * 32, wcol = (wave & 1) * 64;
#pragma unroll
  for (int j = 0; j < 2; ++j) {
    const int col = bn * 128 + wcol + j * 32 + r32;
    const float bs = b2[col], ls = lsg[col];
#pragma unroll
    for (int r = 0; r < 16; ++r) {
      const int row = bm * 64 + wrow + 4 * h + (r & 3) + 8 * (r >> 2);
      out[(size_t)row * 1024 + col] =
          x[(size_t)row * 1024 + col] + (acc[j][r] + bs) * ls;
    }
  }
}

// ---------------- q/k per-head LN (bf16 out) + gelu (fp8 out), one launch
__global__ __launch_bounds__(256) void k_qkvgelu(const u16* __restrict__ f1,
                                                 const float* __restrict__ qg,
                                                 const float* __restrict__ qbb,
                                                 const float* __restrict__ kg,
                                                 const float* __restrict__ kbb,
                                                 u16* __restrict__ q,
                                                 u16* __restrict__ k,
                                                 u8* __restrict__ gel) {
  const int tid = threadIdx.x;
  if (blockIdx.x < 4096) {
    const int row = blockIdx.x;
    const int rem = tid >> 3;
    const int which = rem >> 4, h = rem & 15;
    const int e8 = (tid & 7) * 8;
    u16x8 xv = *(const u16x8*)(f1 + (size_t)row * 3840 + which * 1024 + h * 64 + e8);
    float xf[8];
    float s1 = 0.f, s2 = 0.f;
#pragma unroll
    for (int e = 0; e < 8; ++e) {
      xf[e] = bf2f(xv[e]);
      s1 += xf[e];
      s2 += xf[e] * xf[e];
    }
#pragma unroll
    for (int off = 1; off < 8; off <<= 1) {
      s1 += __shfl_xor(s1, off);
      s2 += __shfl_xor(s2, off);
    }
    const float mean = s1 * (1.f / 64.f);
    const float var = s2 * (1.f / 64.f) - mean * mean;
    const float rstd = rsqrtf(var + 1e-5f);
    const float* g = (which == 0) ? qg : kg;
    const float* bb = (which == 0) ? qbb : kbb;
    float4 g0 = ((const float4*)g)[e8 >> 2], g1 = ((const float4*)g)[(e8 >> 2) + 1];
    float4 b0 = ((const float4*)bb)[e8 >> 2], b1 = ((const float4*)bb)[(e8 >> 2) + 1];
    float gv[8] = {g0.x, g0.y, g0.z, g0.w, g1.x, g1.y, g1.z, g1.w};
    float bv[8] = {b0.x, b0.y, b0.z, b0.w, b1.x, b1.y, b1.z, b1.w};
    u16x8 o;
#pragma unroll
    for (int e = 0; e < 8; ++e) o[e] = f2bf((xf[e] - mean) * rstd * gv[e] + bv[e]);
    const int b = row >> 10, n = row & 1023;
    u16* dst = (which == 0) ? q : k;
    *(u16x8*)(dst + ((size_t)(b * 16 + h) * 1024 + n) * 64 + e8) = o;
  } else {
    const int id = (blockIdx.x - 4096) * 256 + tid;
    const int row = id / 96, c8 = id - row * 96;
    u16x8 xv = *(const u16x8*)(f1 + (size_t)row * 3840 + 3072 + c8 * 8);
    float rr[8];
#pragma unroll
    for (int e = 0; e < 8; ++e) {
      const int col = c8 * 8 + e;
      rr[e] = 0.f;
      if (col < 716) {
        float xx = bf2f(xv[e]);
        rr[e] = 0.5f * xx * (1.f + erff(xx * 0.70710678118654752f));
      }
    }
    int p0 = __builtin_amdgcn_cvt_pk_fp8_f32(rr[0], rr[1], 0, false);
    p0 = __builtin_amdgcn_cvt_pk_fp8_f32(rr[2], rr[3], p0, true);
    int p1 = __builtin_amdgcn_cvt_pk_fp8_f32(rr[4], rr[5], 0, false);
    p1 = __builtin_amdgcn_cvt_pk_fp8_f32(rr[6], rr[7], p1, true);
    uint2 pk;
    pk.x = (unsigned)p0;
    pk.y = (unsigned)p1;
    *(uint2*)(gel + (size_t)row * 768 + c8 * 8) = pk;
  }
}

// ---------------- flash attention v3: 256 threads (4 waves x 16 q-rows), grid 1024.
// Double-buffered K/V staging (T3-minimum pipeline: issue STAGE(t+1) before
// compute(t); the single end-of-iter __syncthreads drains vmcnt AFTER compute
// has covered the load latency). XOR-swizzled unpadded LDS (64-u16 rows,
// 16B chunk pos = c ^ (row&7)); P wave-private (lgkmcnt-ordered, no barrier).
// 4 blocks/CU at 40KB LDS; K/V tile shared by 4 waves (halves L2 traffic).
__global__ __launch_bounds__(256) void k_flash(const u16* __restrict__ q,
                                               const u16* __restrict__ k,
                                               const u16* __restrict__ vt,
                                               u8* __restrict__ xo) {
  __shared__ __align__(16) u16 Kl[2][64 * 64];
  __shared__ __align__(16) u16 Vl[2][64 * 64];
  __shared__ __align__(16) u16 Pl[4 * 16 * 64];
  const int tid = threadIdx.x, wave = tid >> 6, lane = tid & 63;
  const int l15 = lane & 15, quad = lane >> 4;
  // XCD swizzle: 8 bh per XCD (16 q-tiles each) -> K/V (256KB/bh) L2-resident
  const int L = blockIdx.x;
  const int xcd = L & 7, i = L >> 3;
  const int bh = xcd * 8 + (i & 7), qt = i >> 3;  // qt 0..15
  const int qrow0 = qt * 64 + wave * 16;
  const u16* qb = q + ((size_t)bh * 1024 + qrow0) * 64;
  const u16* kb = k + (size_t)bh * 1024 * 64;
  const u16* vb = vt + (size_t)bh * 64 * 1024;
  u16* Pw = Pl + wave * 16 * 64;

  u16x8 qf[2];
#pragma unroll
  for (int kk = 0; kk < 2; ++kk)
    qf[kk] = *(const u16x8*)(qb + (size_t)l15 * 64 + (kk * 4 + quad) * 8);

  f32x4 O[4];
  float lacc[4] = {0.f, 0.f, 0.f, 0.f};
#pragma unroll
  for (int dt = 0; dt < 4; ++dt) O[dt] = f32x4{0.f, 0.f, 0.f, 0.f};

  const int pl7 = l15 & 7;
  // staging geometry: 512 16B chunks per matrix, 2 per thread
  const int r0 = tid >> 3, c0 = (tid & 7) ^ (r0 & 7);
  const int s1 = tid + 256;
  const int r1 = s1 >> 3, c1 = (s1 & 7) ^ (r1 & 7);

  // prologue: stage kv=0 into buffer 0
  load_lds16(kb + (size_t)r0 * 64 + c0 * 8, (u16*)Kl[0] + tid * 8);
  load_lds16(kb + (size_t)r1 * 64 + c1 * 8, (u16*)Kl[0] + s1 * 8);
  load_lds16(vb + (size_t)r0 * 1024 + c0 * 8, (u16*)Vl[0] + tid * 8);
  load_lds16(vb + (size_t)r1 * 1024 + c1 * 8, (u16*)Vl[0] + s1 * 8);
  __syncthreads();  // drains vmcnt -> buf0 ready

  for (int kv = 0; kv < 16; ++kv) {
    const int cur = kv & 1;
    // issue next-tile stage into the other buffer BEFORE computing this one
    if (kv < 15) {
      const size_t ko = (size_t)(kv + 1) * 64;
      load_lds16(kb + (ko + r0) * 64 + c0 * 8, (u16*)Kl[cur ^ 1] + tid * 8);
      load_lds16(kb + (ko + r1) * 64 + c1 * 8, (u16*)Kl[cur ^ 1] + s1 * 8);
      load_lds16(vb + (size_t)r0 * 1024 + ko + c0 * 8, (u16*)Vl[cur ^ 1] + tid * 8);
      load_lds16(vb + (size_t)r1 * 1024 + ko + c1 * 8, (u16*)Vl[cur ^ 1] + s1 * 8);
    }
    const u16* Kc = (const u16*)Kl[cur];
    const u16* Vc = (const u16*)Vl[cur];
    f32x4 S[4];
#pragma unroll
    for (int j = 0; j < 4; ++j) S[j] = f32x4{0.f, 0.f, 0.f, 0.f};
    __builtin_amdgcn_s_setprio(1);
#pragma unroll
    for (int j = 0; j < 4; ++j)
#pragma unroll
      for (int kk = 0; kk < 2; ++kk) {
        const int pos = (kk * 4 + quad) ^ pl7;
        u16x8 bfr = *(const u16x8*)(Kc + (16 * j + l15) * 64 + pos * 8);
        S[j] = mfma16(qf[kk], bfr, S[j]);
      }
    __builtin_amdgcn_s_setprio(0);
    // no-max softmax (|s|<=8 after q/k LN); P wave-private
#pragma unroll
    for (int j = 0; j < 4; ++j)
#pragma unroll
      for (int r = 0; r < 4; ++r) {
        float pv = __expf(S[j][r] * 0.125f);
        lacc[r] += pv;
        const int prow = quad * 4 + r;
        const int pc = 2 * j + (l15 >> 3);
        Pw[prow * 64 + (pc ^ (prow & 7)) * 8 + pl7] = f2bf(pv);
      }
    // same-wave P RAW: force DS write completion before reads
    __builtin_amdgcn_s_waitcnt(0xC07F);  // lgkmcnt(0) only
    __builtin_amdgcn_s_setprio(1);
#pragma unroll
    for (int c = 0; c < 2; ++c) {
      const int pos = (c * 4 + quad) ^ pl7;
      u16x8 pa = *(const u16x8*)(Pw + l15 * 64 + pos * 8);
#pragma unroll
      for (int dt = 0; dt < 4; ++dt) {
        u16x8 vf = *(const u16x8*)(Vc + (16 * dt + l15) * 64 + pos * 8);
        O[dt] = mfma16(pa, vf, O[dt]);
      }
    }
    __builtin_amdgcn_s_setprio(0);
    // one barrier per iter: drains vmcnt(0) (next tile staged) and ensures all
    // waves are done reading buf[cur] before it is overwritten next iter
    __syncthreads();
  }
#pragma unroll
  for (int r = 0; r < 4; ++r) {
#pragma unroll
    for (int off = 1; off < 16; off <<= 1) lacc[r] += __shfl_xor(lacc[r], off);
  }
  const int b = bh >> 4, h = bh & 15;
#pragma unroll
  for (int r = 0; r < 4; ++r) {
    const float inv = 1.f / lacc[r];
    u8* orow = xo + (size_t)(b * 1024 + qrow0 + quad * 4 + r) * 1024 + h * 64;
#pragma unroll
    for (int dt = 0; dt < 4; ++dt) orow[16 * dt + l15] = f2fp8(O[dt][r] * inv);
  }
}

extern "C" void kernel_launch(void* const* d_in, const int* in_sizes, int n_in,
                              void* d_out, int out_size, void* d_ws, size_t ws_size,
                              hipStream_t stream) {
  (void)in_sizes; (void)n_in; (void)out_size; (void)ws_size;
  const float* x      = (const float*)d_in[0];
  const float* norm_g = (const float*)d_in[1];
  const float* norm_b = (const float*)d_in[2];
  const float* W1     = (const float*)d_in[3];
  const float* b1     = (const float*)d_in[4];
  const float* qn_g   = (const float*)d_in[5];
  const float* qn_b   = (const float*)d_in[6];
  const float* kn_g   = (const float*)d_in[7];
  const float* kn_b   = (const float*)d_in[8];
  const float* projW  = (const float*)d_in[9];
  const float* projb  = (const float*)d_in[10];
  const float* mlpW   = (const float*)d_in[11];
  const float* W2     = (const float*)d_in[12];
  const float* b2     = (const float*)d_in[13];
  const float* ls_g   = (const float*)d_in[14];

  char* ws = (char*)d_ws;
  u8*  W1t8 = (u8*)(ws + 0);           // [3840][1024]  3,932,160
  u8*  pWt8 = (u8*)(ws + 3932160);     // [1024][1024]  1,048,576
  u8*  mWt8 = (u8*)(ws + 4980736);     // [1024][768]     786,432
  u8*  W2t8 = (u8*)(ws + 5767168);     // [1024][2048]  2,097,152
  u8*  nx8  = (u8*)(ws + 7864320);     // [4096][1024]  4,194,304 (then xo8)
  u16* f1   = (u16*)(ws + 12058624);   // [4096][3840] 31,457,280 bf16 (then comb fp8)
  u16* qbuf = (u16*)(ws + 43515904);   // [64][1024][64] 8,388,608
  u16* kbuf = (u16*)(ws + 51904512);   // [64][1024][64] 8,388,608
  u16* vtb  = (u16*)(ws + 60293120);   // [64][64][1024] 8,388,608
  u8*  gel8 = (u8*)(ws + 68681728);    // [4096][768]   3,145,728

  k_trcvt_all<<<7680, 256, 0, stream>>>(W1, projW, mlpW, W2, W1t8, pWt8, mWt8, W2t8);
  k_lnx<<<4096, 256, 0, stream>>>(x, norm_g, norm_b, nx8);
  k_gemm1<<<dim3(30, 32), 256, 0, stream>>>(nx8, W1t8, f1, b1);
  k_qkvgelu<<<5632, 256, 0, stream>>>(f1, qn_g, qn_b, kn_g, kn_b, qbuf, kbuf, gel8);
  k_trvt<<<dim3(2, 32, 64), 256, 0, stream>>>(f1, vtb);
  k_flash<<<1024, 256, 0, stream>>>(qbuf, kbuf, vtb, nx8);
  k_gemm_pm<<<dim3(16, 64), 256, 0, stream>>>(nx8, pWt8, gel8, mWt8, (u8*)f1, projb);
  k_gemm_fin<<<dim3(8, 64), 256, 0, stream>>>((u8*)f1, W2t8, (float*)d_out, b2, x,
                                              ls_g);
}

// Round 2
// 230.851 us; speedup vs baseline: 1.0363x; 1.0091x over previous
//
#include <hip/hip_runtime.h>
#include <cstdint>
#include <cstddef>

typedef unsigned short u16;
typedef unsigned char u8;
typedef __attribute__((ext_vector_type(8))) u16 u16x8;
typedef __attribute__((ext_vector_type(8))) __bf16 bf16x8;
typedef __attribute__((ext_vector_type(4))) float f32x4;
typedef __attribute__((ext_vector_type(16))) float f32x16;
typedef __attribute__((ext_vector_type(4))) int i32x4;
typedef __attribute__((ext_vector_type(8))) int i32x8;

__device__ __forceinline__ u16 f2bf(float f) {
  unsigned u = __builtin_bit_cast(unsigned, f);
  return (u16)((u + 0x7FFFu + ((u >> 16) & 1u)) >> 16);
}
__device__ __forceinline__ float bf2f(u16 h) {
  return __builtin_bit_cast(float, (unsigned)h << 16);
}
__device__ __forceinline__ u8 f2fp8(float f) {
  return (u8)(__builtin_amdgcn_cvt_pk_fp8_f32(f, 0.f, 0, false) & 0xFF);
}
__device__ __forceinline__ f32x4 mfma16(u16x8 a, u16x8 b, f32x4 c) {
  return __builtin_amdgcn_mfma_f32_16x16x32_bf16(
      __builtin_bit_cast(bf16x8, a), __builtin_bit_cast(bf16x8, b), c, 0, 0, 0);
}
__device__ __forceinline__ void load_lds16(const void* g, void* l) {
  __builtin_amdgcn_global_load_lds(
      (const __attribute__((address_space(1))) void*)g,
      (__attribute__((address_space(3))) void*)l, 16, 0, 0);
}

// ---------------- fused pre-pass: 4 weight transposes (fp8) + x LayerNorm (fp8)
// L < 7680: transpose blocks; L >= 7680: LN rows.
__global__ __launch_bounds__(256) void k_pre(
    const float* __restrict__ W1, const float* __restrict__ projW,
    const float* __restrict__ mlpW, const float* __restrict__ W2,
    u8* __restrict__ W1t, u8* __restrict__ pWt, u8* __restrict__ mWt,
    u8* __restrict__ W2t, const float* __restrict__ x,
    const float* __restrict__ g, const float* __restrict__ b,
    u8* __restrict__ nx8) {
  __shared__ float t[32][33];
  __shared__ float red[8];
  const int L = blockIdx.x;
  const int tid = threadIdx.x;
  if (L < 7680) {
    const float* src;
    u8* dst;
    int R, C, dR, dC, bx, by;
    if (L < 3840) {
      src = W1; dst = W1t; R = 1024; C = 3788; dR = 1024; dC = 3840;
      bx = L % 120; by = L / 120;
    } else if (L < 4864) {
      int tq = L - 3840;
      src = projW; dst = pWt; R = 1024; C = 1024; dR = 1024; dC = 1024;
      bx = tq & 31; by = tq >> 5;
    } else if (L < 5632) {
      int tq = L - 4864;
      src = mlpW; dst = mWt; R = 716; C = 1024; dR = 768; dC = 1024;
      bx = tq & 31; by = tq >> 5;
    } else {
      int tq = L - 5632;
      src = W2; dst = W2t; R = 2048; C = 1024; dR = 2048; dC = 1024;
      bx = tq & 31; by = tq >> 5;
    }
    const int n0 = bx * 32, k0 = by * 32;
    const int tx = tid & 31, ty = tid >> 5;
#pragma unroll
    for (int j = 0; j < 4; ++j) {
      int kk = k0 + ty + 8 * j, nn = n0 + tx;
      float v = (kk < R && nn < C) ? src[(size_t)kk * C + nn] : 0.f;
      t[ty + 8 * j][tx] = v;
    }
    __syncthreads();
#pragma unroll
    for (int j = 0; j < 4; ++j) {
      int nn = n0 + ty + 8 * j, kk = k0 + tx;
      if (nn < dC && kk < dR) dst[(size_t)nn * dR + kk] = f2fp8(t[tx][ty + 8 * j]);
    }
  } else {
    const int row = L - 7680;
    float4 v = ((const float4*)(x + (size_t)row * 1024))[tid];
    float s = v.x + v.y + v.z + v.w;
    float ss = v.x * v.x + v.y * v.y + v.z * v.z + v.w * v.w;
#pragma unroll
    for (int off = 1; off < 64; off <<= 1) {
      s += __shfl_xor(s, off);
      ss += __shfl_xor(ss, off);
    }
    const int wid = tid >> 6, lane = tid & 63;
    if (lane == 0) { red[wid] = s; red[4 + wid] = ss; }
    __syncthreads();
    s = red[0] + red[1] + red[2] + red[3];
    ss = red[4] + red[5] + red[6] + red[7];
    const float mean = s * (1.f / 1024.f);
    const float var = ss * (1.f / 1024.f) - mean * mean;
    const float rstd = rsqrtf(var + 1e-5f);
    float4 gv = ((const float4*)g)[tid];
    float4 bv = ((const float4*)b)[tid];
    float y0 = (v.x - mean) * rstd * gv.x + bv.x;
    float y1 = (v.y - mean) * rstd * gv.y + bv.y;
    float y2 = (v.z - mean) * rstd * gv.z + bv.z;
    float y3 = (v.w - mean) * rstd * gv.w + bv.w;
    int pk = __builtin_amdgcn_cvt_pk_fp8_f32(y0, y1, 0, false);
    pk = __builtin_amdgcn_cvt_pk_fp8_f32(y2, y3, pk, true);
    ((int*)(nx8 + (size_t)row * 1024))[tid] = pk;
  }
}

// ---------------- MX-fp8 GEMM core 128x128, double-buffered (T3-min pipeline):
// issue STAGE(kt+1) into buf^1 before computing buf; ONE barrier per K-step
// (its vmcnt(0) drain lands after the MFMA cluster has covered load latency).
__device__ __forceinline__ void gemm_fp8_core(const u8* __restrict__ A,
                                              const u8* __restrict__ B, int K,
                                              u8* Alds, u8* Blds,
                                              f32x16 (&acc)[2][2], int tid) {
  const int lane = tid & 63, wave = tid >> 6;
  const int h = lane >> 5, r32 = lane & 31;
  const int wrow = (wave >> 1) * 64, wcol = (wave & 1) * 64;
  const int srow0 = tid >> 2, spos = tid & 3;
  const int nk = K >> 6;
  // prologue: stage kt=0 into buffer 0
#pragma unroll
  for (int p = 0; p < 2; ++p) {
    const int row = p * 64 + srow0;
    const int c = spos ^ ((row >> 1) & 3);
    const size_t go = (size_t)row * K + c * 16;
    load_lds16(A + go, Alds + (p * 256 + tid) * 16);
    load_lds16(B + go, Blds + (p * 256 + tid) * 16);
  }
  __syncthreads();
  for (int kt = 0; kt < nk; ++kt) {
    const int cur = kt & 1;
    const u8* Ac = Alds + cur * 8192;
    const u8* Bc = Blds + cur * 8192;
    if (kt + 1 < nk) {
      u8* An = Alds + (cur ^ 1) * 8192;
      u8* Bn = Blds + (cur ^ 1) * 8192;
#pragma unroll
      for (int p = 0; p < 2; ++p) {
        const int row = p * 64 + srow0;
        const int c = spos ^ ((row >> 1) & 3);
        const size_t go = (size_t)row * K + (size_t)(kt + 1) * 64 + c * 16;
        load_lds16(A + go, An + (p * 256 + tid) * 16);
        load_lds16(B + go, Bn + (p * 256 + tid) * 16);
      }
    }
    i32x8 af[2], bf[2];
#pragma unroll
    for (int t = 0; t < 2; ++t) {
      {
        const int row = wrow + t * 32 + r32;
        const int sw = (row >> 1) & 3;
        i32x4 lo = *(const i32x4*)(Ac + row * 64 + ((2 * h) ^ sw) * 16);
        i32x4 hi = *(const i32x4*)(Ac + row * 64 + ((2 * h + 1) ^ sw) * 16);
        i32x8 a;
        a[0] = lo[0]; a[1] = lo[1]; a[2] = lo[2]; a[3] = lo[3];
        a[4] = hi[0]; a[5] = hi[1]; a[6] = hi[2]; a[7] = hi[3];
        af[t] = a;
      }
      {
        const int row = wcol + t * 32 + r32;
        const int sw = (row >> 1) & 3;
        i32x4 lo = *(const i32x4*)(Bc + row * 64 + ((2 * h) ^ sw) * 16);
        i32x4 hi = *(const i32x4*)(Bc + row * 64 + ((2 * h + 1) ^ sw) * 16);
        i32x8 b8;
        b8[0] = lo[0]; b8[1] = lo[1]; b8[2] = lo[2]; b8[3] = lo[3];
        b8[4] = hi[0]; b8[5] = hi[1]; b8[6] = hi[2]; b8[7] = hi[3];
        bf[t] = b8;
      }
    }
#pragma unroll
    for (int i = 0; i < 2; ++i)
#pragma unroll
      for (int j = 0; j < 2; ++j)
        acc[i][j] = __builtin_amdgcn_mfma_scale_f32_32x32x64_f8f6f4(
            af[i], bf[j], acc[i][j], 0, 0, 0, 0x7F7F7F7F, 0, 0x7F7F7F7F);
    // one barrier: drains vmcnt (next tile staged) + guards buf reuse
    __syncthreads();
  }
}

// ---------------- MX-fp8 GEMM core 64(M)x128(N), double-buffered
__device__ __forceinline__ void gemm_fp8_core64(const u8* __restrict__ A,
                                                const u8* __restrict__ B, int K,
                                                u8* Alds, u8* Blds,
                                                f32x16 (&acc)[2], int tid) {
  const int lane = tid & 63, wave = tid >> 6;
  const int h = lane >> 5, r32 = lane & 31;
  const int wrow = (wave >> 1) * 32, wcol = (wave & 1) * 64;
  const int nk = K >> 6;
  const int ra = tid >> 2, posa = tid & 3;
  const int ca = posa ^ ((ra >> 1) & 3);
  // prologue: stage kt=0 into buffer 0
  load_lds16(A + (size_t)ra * K + ca * 16, Alds + tid * 16);
#pragma unroll
  for (int p = 0; p < 2; ++p) {
    const int s = tid + 256 * p;
    const int r = s >> 2, pos = s & 3;
    const int c = pos ^ ((r >> 1) & 3);
    load_lds16(B + (size_t)r * K + c * 16, Blds + s * 16);
  }
  __syncthreads();
  for (int kt = 0; kt < nk; ++kt) {
    const int cur = kt & 1;
    const u8* Ac = Alds + cur * 4096;
    const u8* Bc = Blds + cur * 8192;
    if (kt + 1 < nk) {
      u8* An = Alds + (cur ^ 1) * 4096;
      u8* Bn = Blds + (cur ^ 1) * 8192;
      const size_t k1 = (size_t)(kt + 1) * 64;
      load_lds16(A + (size_t)ra * K + k1 + ca * 16, An + tid * 16);
#pragma unroll
      for (int p = 0; p < 2; ++p) {
        const int s = tid + 256 * p;
        const int r = s >> 2, pos = s & 3;
        const int c = pos ^ ((r >> 1) & 3);
        load_lds16(B + (size_t)r * K + k1 + c * 16, Bn + s * 16);
      }
    }
    i32x8 af, bf[2];
    {
      const int row = wrow + r32;
      const int sw = (row >> 1) & 3;
      i32x4 lo = *(const i32x4*)(Ac + row * 64 + ((2 * h) ^ sw) * 16);
      i32x4 hi = *(const i32x4*)(Ac + row * 64 + ((2 * h + 1) ^ sw) * 16);
      af[0] = lo[0]; af[1] = lo[1]; af[2] = lo[2]; af[3] = lo[3];
      af[4] = hi[0]; af[5] = hi[1]; af[6] = hi[2]; af[7] = hi[3];
    }
#pragma unroll
    for (int t = 0; t < 2; ++t) {
      const int row = wcol + t * 32 + r32;
      const int sw = (row >> 1) & 3;
      i32x4 lo = *(const i32x4*)(Bc + row * 64 + ((2 * h) ^ sw) * 16);
      i32x4 hi = *(const i32x4*)(Bc + row * 64 + ((2 * h + 1) ^ sw) * 16);
      i32x8 b8;
      b8[0] = lo[0]; b8[1] = lo[1]; b8[2] = lo[2]; b8[3] = lo[3];
      b8[4] = hi[0]; b8[5] = hi[1]; b8[6] = hi[2]; b8[7] = hi[3];
      bf[t] = b8;
    }
#pragma unroll
    for (int j = 0; j < 2; ++j)
      acc[j] = __builtin_amdgcn_mfma_scale_f32_32x32x64_f8f6f4(
          af, bf[j], acc[j], 0, 0, 0, 0x7F7F7F7F, 0, 0x7F7F7F7F);
    __syncthreads();
  }
}

// ---------------- GEMM1: f1[4096][3840] bf16 = nx8 @ W1t^T + b1
__global__ __launch_bounds__(256) void k_gemm1(const u8* __restrict__ nx8,
                                               const u8* __restrict__ W1t,
                                               u16* __restrict__ f1,
                                               const float* __restrict__ b1) {
  __shared__ __align__(16) u8 Alds[2 * 128 * 64];
  __shared__ __align__(16) u8 Blds[2 * 128 * 64];
  const int tid = threadIdx.x, bm = blockIdx.y, bn = blockIdx.x;
  f32x16 acc[2][2];
#pragma unroll
  for (int i = 0; i < 2; ++i)
#pragma unroll
    for (int j = 0; j < 2; ++j)
#pragma unroll
      for (int r = 0; r < 16; ++r) acc[i][j][r] = 0.f;
  gemm_fp8_core(nx8 + (size_t)bm * 128 * 1024, W1t + (size_t)bn * 128 * 1024, 1024,
                Alds, Blds, acc, tid);
  const int lane = tid & 63, wave = tid >> 6;
  const int h = lane >> 5, r32 = lane & 31;
  const int wrow = (wave >> 1) * 64, wcol = (wave & 1) * 64;
#pragma unroll
  for (int i = 0; i < 2; ++i)
#pragma unroll
    for (int j = 0; j < 2; ++j) {
      const int col = bn * 128 + wcol + j * 32 + r32;
      const float bs = (col < 3788) ? b1[col] : 0.f;
#pragma unroll
      for (int r = 0; r < 16; ++r) {
        const int row = bm * 128 + wrow + i * 32 + 4 * h + (r & 3) + 8 * (r >> 2);
        f1[(size_t)row * 3840 + col] = f2bf(acc[i][j][r] + bs);
      }
    }
}

// ---------------- proj + mlp fused (64-row tiles): comb[4096][2048] fp8
__global__ __launch_bounds__(256) void k_gemm_pm(
    const u8* __restrict__ xo, const u8* __restrict__ pWt,
    const u8* __restrict__ gel, const u8* __restrict__ mWt,
    u8* __restrict__ comb, const float* __restrict__ projb) {
  __shared__ __align__(16) u8 Alds[2 * 64 * 64];
  __shared__ __align__(16) u8 Blds[2 * 128 * 64];
  const int tid = threadIdx.x, bm = blockIdx.y, bnq = blockIdx.x;
  const u8* A;
  const u8* B;
  int K, colbase;
  const float* bias;
  if (bnq < 8) {
    A = xo + (size_t)bm * 64 * 1024;
    B = pWt + (size_t)bnq * 128 * 1024;
    K = 1024; colbase = bnq * 128; bias = projb;
  } else {
    A = gel + (size_t)bm * 64 * 768;
    B = mWt + (size_t)(bnq - 8) * 128 * 768;
    K = 768; colbase = 1024 + (bnq - 8) * 128; bias = nullptr;
  }
  f32x16 acc[2];
#pragma unroll
  for (int j = 0; j < 2; ++j)
#pragma unroll
    for (int r = 0; r < 16; ++r) acc[j][r] = 0.f;
  gemm_fp8_core64(A, B, K, Alds, Blds, acc, tid);
  const int lane = tid & 63, wave = tid >> 6;
  const int h = lane >> 5, r32 = lane & 31;
  const int wrow = (wave >> 1) * 32, wcol = (wave & 1) * 64;
#pragma unroll
  for (int j = 0; j < 2; ++j) {
    const int col = colbase + wcol + j * 32 + r32;
    const float bs = (bias != nullptr) ? bias[col] : 0.f;
#pragma unroll
    for (int r = 0; r < 16; ++r) {
      const int row = bm * 64 + wrow + 4 * h + (r & 3) + 8 * (r >> 2);
      comb[(size_t)row * 2048 + col] = f2fp8(acc[j][r] + bs);
    }
  }
}

// ---------------- final (64-row tiles): out = x + (comb @ W2t^T + b2) * ls_g
__global__ __launch_bounds__(256) void k_gemm_fin(const u8* __restrict__ comb,
                                                  const u8* __restrict__ W2t,
                                                  float* __restrict__ out,
                                                  const float* __restrict__ b2,
                                                  const float* __restrict__ x,
                                                  const float* __restrict__ lsg) {
  __shared__ __align__(16) u8 Alds[2 * 64 * 64];
  __shared__ __align__(16) u8 Blds[2 * 128 * 64];
  const int tid = threadIdx.x, bm = blockIdx.y, bn = blockIdx.x;
  f32x16 acc[2];
#pragma unroll
  for (int j = 0; j < 2; ++j)
#pragma unroll
    for (int r = 0; r < 16; ++r) acc[j][r] = 0.f;
  gemm_fp8_core64(comb + (size_t)bm * 64 * 2048, W2t + (size_t)bn * 128 * 2048, 2048,
                  Alds, Blds, acc, tid);
  const int lane = tid & 63, wave = tid >> 6;
  const int h = lane >> 5, r32 = lane & 31;
  const int wrow = (wave >> 1) * 32, wcol = (wave & 1) * 64;
#pragma unroll
  for (int j = 0; j < 2; ++j) {
    const int col = bn * 128 + wcol + j * 32 + r32;
    const float bs = b2[col], ls = lsg[col];
#pragma unroll
    for (int r = 0; r < 16; ++r) {
      const int row = bm * 64 + wrow + 4 * h + (r & 3) + 8 * (r >> 2);
      out[(size_t)row * 1024 + col] =
          x[(size_t)row * 1024 + col] + (acc[j][r] + bs) * ls;
    }
  }
}

// ---------------- fused mid-pass: q/k per-head LN + gelu, plus V^T extraction.
// L < 4096: q/k LN rows; L < 5632: gelu; L >= 5632: V^T 32x32 transpose tiles.
__global__ __launch_bounds__(256) void k_mid(const u16* __restrict__ f1,
                                             const float* __restrict__ qg,
                                             const float* __restrict__ qbb,
                                             const float* __restrict__ kg,
                                             const float* __restrict__ kbb,
                                             u16* __restrict__ q,
                                             u16* __restrict__ k,
                                             u8* __restrict__ gel,
                                             u16* __restrict__ vtb) {
  __shared__ u16 tt[32][33];
  const int tid = threadIdx.x;
  const int L = blockIdx.x;
  if (L < 4096) {
    const int row = L;
    const int rem = tid >> 3;
    const int which = rem >> 4, h = rem & 15;
    const int e8 = (tid & 7) * 8;
    u16x8 xv = *(const u16x8*)(f1 + (size_t)row * 3840 + which * 1024 + h * 64 + e8);
    float xf[8];
    float s1 = 0.f, s2 = 0.f;
#pragma unroll
    for (int e = 0; e < 8; ++e) {
      xf[e] = bf2f(xv[e]);
      s1 += xf[e];
      s2 += xf[e] * xf[e];
    }
#pragma unroll
    for (int off = 1; off < 8; off <<= 1) {
      s1 += __shfl_xor(s1, off);
      s2 += __shfl_xor(s2, off);
    }
    const float mean = s1 * (1.f / 64.f);
    const float var = s2 * (1.f / 64.f) - mean * mean;
    const float rstd = rsqrtf(var + 1e-5f);
    const float* g = (which == 0) ? qg : kg;
    const float* bb = (which == 0) ? qbb : kbb;
    float4 g0 = ((const float4*)g)[e8 >> 2], g1 = ((const float4*)g)[(e8 >> 2) + 1];
    float4 b0 = ((const float4*)bb)[e8 >> 2], b1 = ((const float4*)bb)[(e8 >> 2) + 1];
    float gv[8] = {g0.x, g0.y, g0.z, g0.w, g1.x, g1.y, g1.z, g1.w};
    float bv[8] = {b0.x, b0.y, b0.z, b0.w, b1.x, b1.y, b1.z, b1.w};
    u16x8 o;
#pragma unroll
    for (int e = 0; e < 8; ++e) o[e] = f2bf((xf[e] - mean) * rstd * gv[e] + bv[e]);
    const int b = row >> 10, n = row & 1023;
    u16* dst = (which == 0) ? q : k;
    *(u16x8*)(dst + ((size_t)(b * 16 + h) * 1024 + n) * 64 + e8) = o;
  } else if (L < 5632) {
    const int id = (L - 4096) * 256 + tid;
    const int row = id / 96, c8 = id - row * 96;
    u16x8 xv = *(const u16x8*)(f1 + (size_t)row * 3840 + 3072 + c8 * 8);
    float rr[8];
#pragma unroll
    for (int e = 0; e < 8; ++e) {
      const int col = c8 * 8 + e;
      rr[e] = 0.f;
      if (col < 716) {
        float xx = bf2f(xv[e]);
        rr[e] = 0.5f * xx * (1.f + erff(xx * 0.70710678118654752f));
      }
    }
    int p0 = __builtin_amdgcn_cvt_pk_fp8_f32(rr[0], rr[1], 0, false);
    p0 = __builtin_amdgcn_cvt_pk_fp8_f32(rr[2], rr[3], p0, true);
    int p1 = __builtin_amdgcn_cvt_pk_fp8_f32(rr[4], rr[5], 0, false);
    p1 = __builtin_amdgcn_cvt_pk_fp8_f32(rr[6], rr[7], p1, true);
    uint2 pk;
    pk.x = (unsigned)p0;
    pk.y = (unsigned)p1;
    *(uint2*)(gel + (size_t)row * 768 + c8 * 8) = pk;
  } else {
    const int t = L - 5632;  // [0, 4096): bit0=d-tile, bits[5:1]=n-tile, rest=bh
    const int xq = t & 1, yq = (t >> 1) & 31, z = t >> 6;
    const int b = z >> 4, h = z & 15;
    const int d0 = xq * 32, n0 = yq * 32;
    const int tx = tid & 31, ty = tid >> 5;
#pragma unroll
    for (int j = 0; j < 4; ++j)
      tt[ty + 8 * j][tx] =
          f1[(size_t)(b * 1024 + n0 + ty + 8 * j) * 3840 + 2048 + h * 64 + d0 + tx];
    __syncthreads();
#pragma unroll
    for (int j = 0; j < 4; ++j)
      vtb[(size_t)z * 65536 + (size_t)(d0 + ty + 8 * j) * 1024 + n0 + tx] =
          tt[tx][ty + 8 * j];
  }
}

// ---------------- flash attention v3: 256 threads (4 waves x 16 q-rows), grid 1024.
// Double-buffered K/V staging (T3-minimum pipeline); XOR-swizzled unpadded LDS;
// P wave-private (lgkmcnt-ordered, no barrier). 4 blocks/CU at 40KB LDS.
__global__ __launch_bounds__(256) void k_flash(const u16* __restrict__ q,
                                               const u16* __restrict__ k,
                                               const u16* __restrict__ vt,
                                               u8* __restrict__ xo) {
  __shared__ __align__(16) u16 Kl[2][64 * 64];
  __shared__ __align__(16) u16 Vl[2][64 * 64];
  __shared__ __align__(16) u16 Pl[4 * 16 * 64];
  const int tid = threadIdx.x, wave = tid >> 6, lane = tid & 63;
  const int l15 = lane & 15, quad = lane >> 4;
  const int L = blockIdx.x;
  const int xcd = L & 7, i = L >> 3;
  const int bh = xcd * 8 + (i & 7), qt = i >> 3;  // qt 0..15
  const int qrow0 = qt * 64 + wave * 16;
  const u16* qb = q + ((size_t)bh * 1024 + qrow0) * 64;
  const u16* kb = k + (size_t)bh * 1024 * 64;
  const u16* vb = vt + (size_t)bh * 64 * 1024;
  u16* Pw = Pl + wave * 16 * 64;

  u16x8 qf[2];
#pragma unroll
  for (int kk = 0; kk < 2; ++kk)
    qf[kk] = *(const u16x8*)(qb + (size_t)l15 * 64 + (kk * 4 + quad) * 8);

  f32x4 O[4];
  float lacc[4] = {0.f, 0.f, 0.f, 0.f};
#pragma unroll
  for (int dt = 0; dt < 4; ++dt) O[dt] = f32x4{0.f, 0.f, 0.f, 0.f};

  const int pl7 = l15 & 7;
  const int r0 = tid >> 3, c0 = (tid & 7) ^ (r0 & 7);
  const int s1 = tid + 256;
  const int r1 = s1 >> 3, c1 = (s1 & 7) ^ (r1 & 7);

  load_lds16(kb + (size_t)r0 * 64 + c0 * 8, (u16*)Kl[0] + tid * 8);
  load_lds16(kb + (size_t)r1 * 64 + c1 * 8, (u16*)Kl[0] + s1 * 8);
  load_lds16(vb + (size_t)r0 * 1024 + c0 * 8, (u16*)Vl[0] + tid * 8);
  load_lds16(vb + (size_t)r1 * 1024 + c1 * 8, (u16*)Vl[0] + s1 * 8);
  __syncthreads();

  for (int kv = 0; kv < 16; ++kv) {
    const int cur = kv & 1;
    if (kv < 15) {
      const size_t ko = (size_t)(kv + 1) * 64;
      load_lds16(kb + (ko + r0) * 64 + c0 * 8, (u16*)Kl[cur ^ 1] + tid * 8);
      load_lds16(kb + (ko + r1) * 64 + c1 * 8, (u16*)Kl[cur ^ 1] + s1 * 8);
      load_lds16(vb + (size_t)r0 * 1024 + ko + c0 * 8, (u16*)Vl[cur ^ 1] + tid * 8);
      load_lds16(vb + (size_t)r1 * 1024 + ko + c1 * 8, (u16*)Vl[cur ^ 1] + s1 * 8);
    }
    const u16* Kc = (const u16*)Kl[cur];
    const u16* Vc = (const u16*)Vl[cur];
    f32x4 S[4];
#pragma unroll
    for (int j = 0; j < 4; ++j) S[j] = f32x4{0.f, 0.f, 0.f, 0.f};
    __builtin_amdgcn_s_setprio(1);
#pragma unroll
    for (int j = 0; j < 4; ++j)
#pragma unroll
      for (int kk = 0; kk < 2; ++kk) {
        const int pos = (kk * 4 + quad) ^ pl7;
        u16x8 bfr = *(const u16x8*)(Kc + (16 * j + l15) * 64 + pos * 8);
        S[j] = mfma16(qf[kk], bfr, S[j]);
      }
    __builtin_amdgcn_s_setprio(0);
#pragma unroll
    for (int j = 0; j < 4; ++j)
#pragma unroll
      for (int r = 0; r < 4; ++r) {
        float pv = __expf(S[j][r] * 0.125f);
        lacc[r] += pv;
        const int prow = quad * 4 + r;
        const int pc = 2 * j + (l15 >> 3);
        Pw[prow * 64 + (pc ^ (prow & 7)) * 8 + pl7] = f2bf(pv);
      }
    __builtin_amdgcn_s_waitcnt(0xC07F);  // lgkmcnt(0) only
    __builtin_amdgcn_s_setprio(1);
#pragma unroll
    for (int c = 0; c < 2; ++c) {
      const int pos = (c * 4 + quad) ^ pl7;
      u16x8 pa = *(const u16x8*)(Pw + l15 * 64 + pos * 8);
#pragma unroll
      for (int dt = 0; dt < 4; ++dt) {
        u16x8 vf = *(const u16x8*)(Vc + (16 * dt + l15) * 64 + pos * 8);
        O[dt] = mfma16(pa, vf, O[dt]);
      }
    }
    __builtin_amdgcn_s_setprio(0);
    __syncthreads();
  }
#pragma unroll
  for (int r = 0; r < 4; ++r) {
#pragma unroll
    for (int off = 1; off < 16; off <<= 1) lacc[r] += __shfl_xor(lacc[r], off);
  }
  const int b = bh >> 4, h = bh & 15;
#pragma unroll
  for (int r = 0; r < 4; ++r) {
    const float inv = 1.f / lacc[r];
    u8* orow = xo + (size_t)(b * 1024 + qrow0 + quad * 4 + r) * 1024 + h * 64;
#pragma unroll
    for (int dt = 0; dt < 4; ++dt) orow[16 * dt + l15] = f2fp8(O[dt][r] * inv);
  }
}

extern "C" void kernel_launch(void* const* d_in, const int* in_sizes, int n_in,
                              void* d_out, int out_size, void* d_ws, size_t ws_size,
                              hipStream_t stream) {
  (void)in_sizes; (void)n_in; (void)out_size; (void)ws_size;
  const float* x      = (const float*)d_in[0];
  const float* norm_g = (const float*)d_in[1];
  const float* norm_b = (const float*)d_in[2];
  const float* W1     = (const float*)d_in[3];
  const float* b1     = (const float*)d_in[4];
  const float* qn_g   = (const float*)d_in[5];
  const float* qn_b   = (const float*)d_in[6];
  const float* kn_g   = (const float*)d_in[7];
  const float* kn_b   = (const float*)d_in[8];
  const float* projW  = (const float*)d_in[9];
  const float* projb  = (const float*)d_in[10];
  const float* mlpW   = (const float*)d_in[11];
  const float* W2     = (const float*)d_in[12];
  const float* b2     = (const float*)d_in[13];
  const float* ls_g   = (const float*)d_in[14];

  char* ws = (char*)d_ws;
  u8*  W1t8 = (u8*)(ws + 0);           // [3840][1024]  3,932,160
  u8*  pWt8 = (u8*)(ws + 3932160);     // [1024][1024]  1,048,576
  u8*  mWt8 = (u8*)(ws + 4980736);     // [1024][768]     786,432
  u8*  W2t8 = (u8*)(ws + 5767168);     // [1024][2048]  2,097,152
  u8*  nx8  = (u8*)(ws + 7864320);     // [4096][1024]  4,194,304 (then xo8)
  u16* f1   = (u16*)(ws + 12058624);   // [4096][3840] 31,457,280 bf16 (then comb fp8)
  u16* qbuf = (u16*)(ws + 43515904);   // [64][1024][64] 8,388,608
  u16* kbuf = (u16*)(ws + 51904512);   // [64][1024][64] 8,388,608
  u16* vtb  = (u16*)(ws + 60293120);   // [64][64][1024] 8,388,608
  u8*  gel8 = (u8*)(ws + 68681728);    // [4096][768]   3,145,728

  k_pre<<<11776, 256, 0, stream>>>(W1, projW, mlpW, W2, W1t8, pWt8, mWt8, W2t8,
                                   x, norm_g, norm_b, nx8);
  k_gemm1<<<dim3(30, 32), 256, 0, stream>>>(nx8, W1t8, f1, b1);
  k_mid<<<9728, 256, 0, stream>>>(f1, qn_g, qn_b, kn_g, kn_b, qbuf, kbuf, gel8,
                                  vtb);
  k_flash<<<1024, 256, 0, stream>>>(qbuf, kbuf, vtb, nx8);
  k_gemm_pm<<<dim3(16, 64), 256, 0, stream>>>(nx8, pWt8, gel8, mWt8, (u8*)f1, projb);
  k_gemm_fin<<<dim3(8, 64), 256, 0, stream>>>((u8*)f1, W2t8, (float*)d_out, b2, x,
                                              ls_g);
}

// Round 3
// 228.783 us; speedup vs baseline: 1.0457x; 1.0090x over previous
//
#include <hip/hip_runtime.h>
#include <cstdint>
#include <cstddef>

typedef unsigned short u16;
typedef unsigned char u8;
typedef __attribute__((ext_vector_type(8))) u16 u16x8;
typedef __attribute__((ext_vector_type(8))) __bf16 bf16x8;
typedef __attribute__((ext_vector_type(4))) float f32x4;
typedef __attribute__((ext_vector_type(16))) float f32x16;
typedef __attribute__((ext_vector_type(4))) int i32x4;
typedef __attribute__((ext_vector_type(8))) int i32x8;
typedef __attribute__((ext_vector_type(2))) int i32x2;

__device__ __forceinline__ u16 f2bf(float f) {
  unsigned u = __builtin_bit_cast(unsigned, f);
  return (u16)((u + 0x7FFFu + ((u >> 16) & 1u)) >> 16);
}
__device__ __forceinline__ float bf2f(u16 h) {
  return __builtin_bit_cast(float, (unsigned)h << 16);
}
__device__ __forceinline__ u8 f2fp8(float f) {
  return (u8)(__builtin_amdgcn_cvt_pk_fp8_f32(f, 0.f, 0, false) & 0xFF);
}
__device__ __forceinline__ f32x4 mfma16(u16x8 a, u16x8 b, f32x4 c) {
  return __builtin_amdgcn_mfma_f32_16x16x32_bf16(
      __builtin_bit_cast(bf16x8, a), __builtin_bit_cast(bf16x8, b), c, 0, 0, 0);
}
__device__ __forceinline__ f32x16 mfma32(u16x8 a, u16x8 b, f32x16 c) {
  return __builtin_amdgcn_mfma_f32_32x32x16_bf16(
      __builtin_bit_cast(bf16x8, a), __builtin_bit_cast(bf16x8, b), c, 0, 0, 0);
}
__device__ __forceinline__ unsigned cvtpk_bf16(float lo, float hi) {
  unsigned r;
  asm("v_cvt_pk_bf16_f32 %0, %1, %2" : "=v"(r) : "v"(lo), "v"(hi));
  return r;
}
// a' = [a_lo32, b_lo32]; b' = [a_hi32, b_hi32]
__device__ __forceinline__ void plswap(unsigned& a, unsigned& b) {
  i32x2 r = __builtin_amdgcn_permlane32_swap((int)a, (int)b, false, false);
  a = (unsigned)r[0];
  b = (unsigned)r[1];
}
__device__ __forceinline__ void load_lds16(const void* g, void* l) {
  __builtin_amdgcn_global_load_lds(
      (const __attribute__((address_space(1))) void*)g,
      (__attribute__((address_space(3))) void*)l, 16, 0, 0);
}

// ---------------- fused pre-pass: 4 weight transposes (fp8) + x LayerNorm (fp8)
// L < 7680: transpose blocks; L >= 7680: LN rows.
__global__ __launch_bounds__(256) void k_pre(
    const float* __restrict__ W1, const float* __restrict__ projW,
    const float* __restrict__ mlpW, const float* __restrict__ W2,
    u8* __restrict__ W1t, u8* __restrict__ pWt, u8* __restrict__ mWt,
    u8* __restrict__ W2t, const float* __restrict__ x,
    const float* __restrict__ g, const float* __restrict__ b,
    u8* __restrict__ nx8) {
  __shared__ float t[32][33];
  __shared__ float red[8];
  const int L = blockIdx.x;
  const int tid = threadIdx.x;
  if (L < 7680) {
    const float* src;
    u8* dst;
    int R, C, dR, dC, bx, by;
    if (L < 3840) {
      src = W1; dst = W1t; R = 1024; C = 3788; dR = 1024; dC = 3840;
      bx = L % 120; by = L / 120;
    } else if (L < 4864) {
      int tq = L - 3840;
      src = projW; dst = pWt; R = 1024; C = 1024; dR = 1024; dC = 1024;
      bx = tq & 31; by = tq >> 5;
    } else if (L < 5632) {
      int tq = L - 4864;
      src = mlpW; dst = mWt; R = 716; C = 1024; dR = 768; dC = 1024;
      bx = tq & 31; by = tq >> 5;
    } else {
      int tq = L - 5632;
      src = W2; dst = W2t; R = 2048; C = 1024; dR = 2048; dC = 1024;
      bx = tq & 31; by = tq >> 5;
    }
    const int n0 = bx * 32, k0 = by * 32;
    const int tx = tid & 31, ty = tid >> 5;
#pragma unroll
    for (int j = 0; j < 4; ++j) {
      int kk = k0 + ty + 8 * j, nn = n0 + tx;
      float v = (kk < R && nn < C) ? src[(size_t)kk * C + nn] : 0.f;
      t[ty + 8 * j][tx] = v;
    }
    __syncthreads();
#pragma unroll
    for (int j = 0; j < 4; ++j) {
      int nn = n0 + ty + 8 * j, kk = k0 + tx;
      if (nn < dC && kk < dR) dst[(size_t)nn * dR + kk] = f2fp8(t[tx][ty + 8 * j]);
    }
  } else {
    const int row = L - 7680;
    float4 v = ((const float4*)(x + (size_t)row * 1024))[tid];
    float s = v.x + v.y + v.z + v.w;
    float ss = v.x * v.x + v.y * v.y + v.z * v.z + v.w * v.w;
#pragma unroll
    for (int off = 1; off < 64; off <<= 1) {
      s += __shfl_xor(s, off);
      ss += __shfl_xor(ss, off);
    }
    const int wid = tid >> 6, lane = tid & 63;
    if (lane == 0) { red[wid] = s; red[4 + wid] = ss; }
    __syncthreads();
    s = red[0] + red[1] + red[2] + red[3];
    ss = red[4] + red[5] + red[6] + red[7];
    const float mean = s * (1.f / 1024.f);
    const float var = ss * (1.f / 1024.f) - mean * mean;
    const float rstd = rsqrtf(var + 1e-5f);
    float4 gv = ((const float4*)g)[tid];
    float4 bv = ((const float4*)b)[tid];
    float y0 = (v.x - mean) * rstd * gv.x + bv.x;
    float y1 = (v.y - mean) * rstd * gv.y + bv.y;
    float y2 = (v.z - mean) * rstd * gv.z + bv.z;
    float y3 = (v.w - mean) * rstd * gv.w + bv.w;
    int pk = __builtin_amdgcn_cvt_pk_fp8_f32(y0, y1, 0, false);
    pk = __builtin_amdgcn_cvt_pk_fp8_f32(y2, y3, pk, true);
    ((int*)(nx8 + (size_t)row * 1024))[tid] = pk;
  }
}

// ---------------- MX-fp8 GEMM core 128x128, double-buffered (T3-min pipeline)
__device__ __forceinline__ void gemm_fp8_core(const u8* __restrict__ A,
                                              const u8* __restrict__ B, int K,
                                              u8* Alds, u8* Blds,
                                              f32x16 (&acc)[2][2], int tid) {
  const int lane = tid & 63, wave = tid >> 6;
  const int h = lane >> 5, r32 = lane & 31;
  const int wrow = (wave >> 1) * 64, wcol = (wave & 1) * 64;
  const int srow0 = tid >> 2, spos = tid & 3;
  const int nk = K >> 6;
#pragma unroll
  for (int p = 0; p < 2; ++p) {
    const int row = p * 64 + srow0;
    const int c = spos ^ ((row >> 1) & 3);
    const size_t go = (size_t)row * K + c * 16;
    load_lds16(A + go, Alds + (p * 256 + tid) * 16);
    load_lds16(B + go, Blds + (p * 256 + tid) * 16);
  }
  __syncthreads();
  for (int kt = 0; kt < nk; ++kt) {
    const int cur = kt & 1;
    const u8* Ac = Alds + cur * 8192;
    const u8* Bc = Blds + cur * 8192;
    if (kt + 1 < nk) {
      u8* An = Alds + (cur ^ 1) * 8192;
      u8* Bn = Blds + (cur ^ 1) * 8192;
#pragma unroll
      for (int p = 0; p < 2; ++p) {
        const int row = p * 64 + srow0;
        const int c = spos ^ ((row >> 1) & 3);
        const size_t go = (size_t)row * K + (size_t)(kt + 1) * 64 + c * 16;
        load_lds16(A + go, An + (p * 256 + tid) * 16);
        load_lds16(B + go, Bn + (p * 256 + tid) * 16);
      }
    }
    i32x8 af[2], bf[2];
#pragma unroll
    for (int t = 0; t < 2; ++t) {
      {
        const int row = wrow + t * 32 + r32;
        const int sw = (row >> 1) & 3;
        i32x4 lo = *(const i32x4*)(Ac + row * 64 + ((2 * h) ^ sw) * 16);
        i32x4 hi = *(const i32x4*)(Ac + row * 64 + ((2 * h + 1) ^ sw) * 16);
        i32x8 a;
        a[0] = lo[0]; a[1] = lo[1]; a[2] = lo[2]; a[3] = lo[3];
        a[4] = hi[0]; a[5] = hi[1]; a[6] = hi[2]; a[7] = hi[3];
        af[t] = a;
      }
      {
        const int row = wcol + t * 32 + r32;
        const int sw = (row >> 1) & 3;
        i32x4 lo = *(const i32x4*)(Bc + row * 64 + ((2 * h) ^ sw) * 16);
        i32x4 hi = *(const i32x4*)(Bc + row * 64 + ((2 * h + 1) ^ sw) * 16);
        i32x8 b8;
        b8[0] = lo[0]; b8[1] = lo[1]; b8[2] = lo[2]; b8[3] = lo[3];
        b8[4] = hi[0]; b8[5] = hi[1]; b8[6] = hi[2]; b8[7] = hi[3];
        bf[t] = b8;
      }
    }
#pragma unroll
    for (int i = 0; i < 2; ++i)
#pragma unroll
      for (int j = 0; j < 2; ++j)
        acc[i][j] = __builtin_amdgcn_mfma_scale_f32_32x32x64_f8f6f4(
            af[i], bf[j], acc[i][j], 0, 0, 0, 0x7F7F7F7F, 0, 0x7F7F7F7F);
    __syncthreads();
  }
}

// ---------------- MX-fp8 GEMM core 64(M)x128(N), double-buffered
__device__ __forceinline__ void gemm_fp8_core64(const u8* __restrict__ A,
                                                const u8* __restrict__ B, int K,
                                                u8* Alds, u8* Blds,
                                                f32x16 (&acc)[2], int tid) {
  const int lane = tid & 63, wave = tid >> 6;
  const int h = lane >> 5, r32 = lane & 31;
  const int wrow = (wave >> 1) * 32, wcol = (wave & 1) * 64;
  const int nk = K >> 6;
  const int ra = tid >> 2, posa = tid & 3;
  const int ca = posa ^ ((ra >> 1) & 3);
  load_lds16(A + (size_t)ra * K + ca * 16, Alds + tid * 16);
#pragma unroll
  for (int p = 0; p < 2; ++p) {
    const int s = tid + 256 * p;
    const int r = s >> 2, pos = s & 3;
    const int c = pos ^ ((r >> 1) & 3);
    load_lds16(B + (size_t)r * K + c * 16, Blds + s * 16);
  }
  __syncthreads();
  for (int kt = 0; kt < nk; ++kt) {
    const int cur = kt & 1;
    const u8* Ac = Alds + cur * 4096;
    const u8* Bc = Blds + cur * 8192;
    if (kt + 1 < nk) {
      u8* An = Alds + (cur ^ 1) * 4096;
      u8* Bn = Blds + (cur ^ 1) * 8192;
      const size_t k1 = (size_t)(kt + 1) * 64;
      load_lds16(A + (size_t)ra * K + k1 + ca * 16, An + tid * 16);
#pragma unroll
      for (int p = 0; p < 2; ++p) {
        const int s = tid + 256 * p;
        const int r = s >> 2, pos = s & 3;
        const int c = pos ^ ((r >> 1) & 3);
        load_lds16(B + (size_t)r * K + k1 + c * 16, Bn + s * 16);
      }
    }
    i32x8 af, bf[2];
    {
      const int row = wrow + r32;
      const int sw = (row >> 1) & 3;
      i32x4 lo = *(const i32x4*)(Ac + row * 64 + ((2 * h) ^ sw) * 16);
      i32x4 hi = *(const i32x4*)(Ac + row * 64 + ((2 * h + 1) ^ sw) * 16);
      af[0] = lo[0]; af[1] = lo[1]; af[2] = lo[2]; af[3] = lo[3];
      af[4] = hi[0]; af[5] = hi[1]; af[6] = hi[2]; af[7] = hi[3];
    }
#pragma unroll
    for (int t = 0; t < 2; ++t) {
      const int row = wcol + t * 32 + r32;
      const int sw = (row >> 1) & 3;
      i32x4 lo = *(const i32x4*)(Bc + row * 64 + ((2 * h) ^ sw) * 16);
      i32x4 hi = *(const i32x4*)(Bc + row * 64 + ((2 * h + 1) ^ sw) * 16);
      i32x8 b8;
      b8[0] = lo[0]; b8[1] = lo[1]; b8[2] = lo[2]; b8[3] = lo[3];
      b8[4] = hi[0]; b8[5] = hi[1]; b8[6] = hi[2]; b8[7] = hi[3];
      bf[t] = b8;
    }
#pragma unroll
    for (int j = 0; j < 2; ++j)
      acc[j] = __builtin_amdgcn_mfma_scale_f32_32x32x64_f8f6f4(
          af, bf[j], acc[j], 0, 0, 0, 0x7F7F7F7F, 0, 0x7F7F7F7F);
    __syncthreads();
  }
}

// ---------------- GEMM1: f1[4096][3840] bf16 = nx8 @ W1t^T + b1
__global__ __launch_bounds__(256) void k_gemm1(const u8* __restrict__ nx8,
                                               const u8* __restrict__ W1t,
                                               u16* __restrict__ f1,
                                               const float* __restrict__ b1) {
  __shared__ __align__(16) u8 Alds[2 * 128 * 64];
  __shared__ __align__(16) u8 Blds[2 * 128 * 64];
  const int tid = threadIdx.x, bm = blockIdx.y, bn = blockIdx.x;
  f32x16 acc[2][2];
#pragma unroll
  for (int i = 0; i < 2; ++i)
#pragma unroll
    for (int j = 0; j < 2; ++j)
#pragma unroll
      for (int r = 0; r < 16; ++r) acc[i][j][r] = 0.f;
  gemm_fp8_core(nx8 + (size_t)bm * 128 * 1024, W1t + (size_t)bn * 128 * 1024, 1024,
                Alds, Blds, acc, tid);
  const int lane = tid & 63, wave = tid >> 6;
  const int h = lane >> 5, r32 = lane & 31;
  const int wrow = (wave >> 1) * 64, wcol = (wave & 1) * 64;
#pragma unroll
  for (int i = 0; i < 2; ++i)
#pragma unroll
    for (int j = 0; j < 2; ++j) {
      const int col = bn * 128 + wcol + j * 32 + r32;
      const float bs = (col < 3788) ? b1[col] : 0.f;
#pragma unroll
      for (int r = 0; r < 16; ++r) {
        const int row = bm * 128 + wrow + i * 32 + 4 * h + (r & 3) + 8 * (r >> 2);
        f1[(size_t)row * 3840 + col] = f2bf(acc[i][j][r] + bs);
      }
    }
}

// ---------------- proj + mlp fused (64-row tiles): comb[4096][2048] fp8
__global__ __launch_bounds__(256) void k_gemm_pm(
    const u8* __restrict__ xo, const u8* __restrict__ pWt,
    const u8* __restrict__ gel, const u8* __restrict__ mWt,
    u8* __restrict__ comb, const float* __restrict__ projb) {
  __shared__ __align__(16) u8 Alds[2 * 64 * 64];
  __shared__ __align__(16) u8 Blds[2 * 128 * 64];
  const int tid = threadIdx.x, bm = blockIdx.y, bnq = blockIdx.x;
  const u8* A;
  const u8* B;
  int K, colbase;
  const float* bias;
  if (bnq < 8) {
    A = xo + (size_t)bm * 64 * 1024;
    B = pWt + (size_t)bnq * 128 * 1024;
    K = 1024; colbase = bnq * 128; bias = projb;
  } else {
    A = gel + (size_t)bm * 64 * 768;
    B = mWt + (size_t)(bnq - 8) * 128 * 768;
    K = 768; colbase = 1024 + (bnq - 8) * 128; bias = nullptr;
  }
  f32x16 acc[2];
#pragma unroll
  for (int j = 0; j < 2; ++j)
#pragma unroll
    for (int r = 0; r < 16; ++r) acc[j][r] = 0.f;
  gemm_fp8_core64(A, B, K, Alds, Blds, acc, tid);
  const int lane = tid & 63, wave = tid >> 6;
  const int h = lane >> 5, r32 = lane & 31;
  const int wrow = (wave >> 1) * 32, wcol = (wave & 1) * 64;
#pragma unroll
  for (int j = 0; j < 2; ++j) {
    const int col = colbase + wcol + j * 32 + r32;
    const float bs = (bias != nullptr) ? bias[col] : 0.f;
#pragma unroll
    for (int r = 0; r < 16; ++r) {
      const int row = bm * 64 + wrow + 4 * h + (r & 3) + 8 * (r >> 2);
      comb[(size_t)row * 2048 + col] = f2fp8(acc[j][r] + bs);
    }
  }
}

// ---------------- final (64-row tiles): out = x + (comb @ W2t^T + b2) * ls_g
__global__ __launch_bounds__(256) void k_gemm_fin(const u8* __restrict__ comb,
                                                  const u8* __restrict__ W2t,
                                                  float* __restrict__ out,
                                                  const float* __restrict__ b2,
                                                  const float* __restrict__ x,
                                                  const float* __restrict__ lsg) {
  __shared__ __align__(16) u8 Alds[2 * 64 * 64];
  __shared__ __align__(16) u8 Blds[2 * 128 * 64];
  const int tid = threadIdx.x, bm = blockIdx.y, bn = blockIdx.x;
  f32x16 acc[2];
#pragma unroll
  for (int j = 0; j < 2; ++j)
#pragma unroll
    for (int r = 0; r < 16; ++r) acc[j][r] = 0.f;
  gemm_fp8_core64(comb + (size_t)bm * 64 * 2048, W2t + (size_t)bn * 128 * 2048, 2048,
                  Alds, Blds, acc, tid);
  const int lane = tid & 63, wave = tid >> 6;
  const int h = lane >> 5, r32 = lane & 31;
  const int wrow = (wave >> 1) * 32, wcol = (wave & 1) * 64;
#pragma unroll
  for (int j = 0; j < 2; ++j) {
    const int col = bn * 128 + wcol + j * 32 + r32;
    const float bs = b2[col], ls = lsg[col];
#pragma unroll
    for (int r = 0; r < 16; ++r) {
      const int row = bm * 64 + wrow + 4 * h + (r & 3) + 8 * (r >> 2);
      out[(size_t)row * 1024 + col] =
          x[(size_t)row * 1024 + col] + (acc[j][r] + bs) * ls;
    }
  }
}

// ---------------- fused mid-pass: q/k per-head LN + gelu, plus V^T extraction.
__global__ __launch_bounds__(256) void k_mid(const u16* __restrict__ f1,
                                             const float* __restrict__ qg,
                                             const float* __restrict__ qbb,
                                             const float* __restrict__ kg,
                                             const float* __restrict__ kbb,
                                             u16* __restrict__ q,
                                             u16* __restrict__ k,
                                             u8* __restrict__ gel,
                                             u16* __restrict__ vtb) {
  __shared__ u16 tt[32][33];
  const int tid = threadIdx.x;
  const int L = blockIdx.x;
  if (L < 4096) {
    const int row = L;
    const int rem = tid >> 3;
    const int which = rem >> 4, h = rem & 15;
    const int e8 = (tid & 7) * 8;
    u16x8 xv = *(const u16x8*)(f1 + (size_t)row * 3840 + which * 1024 + h * 64 + e8);
    float xf[8];
    float s1 = 0.f, s2 = 0.f;
#pragma unroll
    for (int e = 0; e < 8; ++e) {
      xf[e] = bf2f(xv[e]);
      s1 += xf[e];
      s2 += xf[e] * xf[e];
    }
#pragma unroll
    for (int off = 1; off < 8; off <<= 1) {
      s1 += __shfl_xor(s1, off);
      s2 += __shfl_xor(s2, off);
    }
    const float mean = s1 * (1.f / 64.f);
    const float var = s2 * (1.f / 64.f) - mean * mean;
    const float rstd = rsqrtf(var + 1e-5f);
    const float* g = (which == 0) ? qg : kg;
    const float* bb = (which == 0) ? qbb : kbb;
    float4 g0 = ((const float4*)g)[e8 >> 2], g1 = ((const float4*)g)[(e8 >> 2) + 1];
    float4 b0 = ((const float4*)bb)[e8 >> 2], b1 = ((const float4*)bb)[(e8 >> 2) + 1];
    float gv[8] = {g0.x, g0.y, g0.z, g0.w, g1.x, g1.y, g1.z, g1.w};
    float bv[8] = {b0.x, b0.y, b0.z, b0.w, b1.x, b1.y, b1.z, b1.w};
    u16x8 o;
#pragma unroll
    for (int e = 0; e < 8; ++e) o[e] = f2bf((xf[e] - mean) * rstd * gv[e] + bv[e]);
    const int b = row >> 10, n = row & 1023;
    u16* dst = (which == 0) ? q : k;
    *(u16x8*)(dst + ((size_t)(b * 16 + h) * 1024 + n) * 64 + e8) = o;
  } else if (L < 5632) {
    const int id = (L - 4096) * 256 + tid;
    const int row = id / 96, c8 = id - row * 96;
    u16x8 xv = *(const u16x8*)(f1 + (size_t)row * 3840 + 3072 + c8 * 8);
    float rr[8];
#pragma unroll
    for (int e = 0; e < 8; ++e) {
      const int col = c8 * 8 + e;
      rr[e] = 0.f;
      if (col < 716) {
        float xx = bf2f(xv[e]);
        rr[e] = 0.5f * xx * (1.f + erff(xx * 0.70710678118654752f));
      }
    }
    int p0 = __builtin_amdgcn_cvt_pk_fp8_f32(rr[0], rr[1], 0, false);
    p0 = __builtin_amdgcn_cvt_pk_fp8_f32(rr[2], rr[3], p0, true);
    int p1 = __builtin_amdgcn_cvt_pk_fp8_f32(rr[4], rr[5], 0, false);
    p1 = __builtin_amdgcn_cvt_pk_fp8_f32(rr[6], rr[7], p1, true);
    uint2 pk;
    pk.x = (unsigned)p0;
    pk.y = (unsigned)p1;
    *(uint2*)(gel + (size_t)row * 768 + c8 * 8) = pk;
  } else {
    const int t = L - 5632;
    const int xq = t & 1, yq = (t >> 1) & 31, z = t >> 6;
    const int b = z >> 4, h = z & 15;
    const int d0 = xq * 32, n0 = yq * 32;
    const int tx = tid & 31, ty = tid >> 5;
#pragma unroll
    for (int j = 0; j < 4; ++j)
      tt[ty + 8 * j][tx] =
          f1[(size_t)(b * 1024 + n0 + ty + 8 * j) * 3840 + 2048 + h * 64 + d0 + tx];
    __syncthreads();
#pragma unroll
    for (int j = 0; j < 4; ++j)
      vtb[(size_t)z * 65536 + (size_t)(d0 + ty + 8 * j) * 1024 + n0 + tx] =
          tt[tx][ty + 8 * j];
  }
}

// ---------------- flash attention v4: 128 threads = 2 waves x 32 q-rows, grid 1024.
// Swapped QK^T (S^T = mfma32(K, Q): col=lane&31=q) -> each lane owns one q-row's
// P values -> softmax sum is lane-local; P rebuilt in-register for PV via
// v_cvt_pk_bf16_f32 + permlane32_swap (T12) -> zero P LDS traffic.
// 32x32x16 MFMA halves K/V LDS read traffic vs 16-row waves.
// Double-buffered K/V staging (T3-min), XOR-swizzled LDS, 32KB LDS.
__global__ __launch_bounds__(128) void k_flash(const u16* __restrict__ q,
                                               const u16* __restrict__ k,
                                               const u16* __restrict__ vt,
                                               u8* __restrict__ xo) {
  __shared__ __align__(16) u16 Kl[2][64 * 64];
  __shared__ __align__(16) u16 Vl[2][64 * 64];
  const int tid = threadIdx.x, wave = tid >> 6, lane = tid & 63;
  const int l31 = lane & 31, h = lane >> 5;
  const int L = blockIdx.x;
  const int xcd = L & 7, i = L >> 3;
  const int bh = xcd * 8 + (i & 7), qt = i >> 3;  // qt 0..15
  const int qrow0 = qt * 64 + wave * 32;
  const u16* qb = q + ((size_t)bh * 1024 + qrow0) * 64;
  const u16* kb = k + (size_t)bh * 1024 * 64;
  const u16* vb = vt + (size_t)bh * 64 * 1024;

  // Q as B-frag: lane holds Q[q=l31][d = ds*16 + h*8 + e]
  u16x8 qf[4];
#pragma unroll
  for (int ds = 0; ds < 4; ++ds)
    qf[ds] = *(const u16x8*)(qb + (size_t)l31 * 64 + ds * 16 + h * 8);

  f32x16 O[2];
#pragma unroll
  for (int d2 = 0; d2 < 2; ++d2)
#pragma unroll
    for (int r = 0; r < 16; ++r) O[d2][r] = 0.f;
  float lacc = 0.f;

  // staging geometry: 512 chunks of 16B per tile, 4 per thread
  int sr[4], sc[4];
#pragma unroll
  for (int p = 0; p < 4; ++p) {
    const int s = tid + 128 * p;
    sr[p] = s >> 3;
    sc[p] = (s & 7) ^ (sr[p] & 7);
  }

  // prologue: stage kv=0 into buffer 0
#pragma unroll
  for (int p = 0; p < 4; ++p) {
    const int s = tid + 128 * p;
    load_lds16(kb + (size_t)sr[p] * 64 + sc[p] * 8, (u16*)Kl[0] + s * 8);
    load_lds16(vb + (size_t)sr[p] * 1024 + sc[p] * 8, (u16*)Vl[0] + s * 8);
  }
  __syncthreads();

  for (int kv = 0; kv < 16; ++kv) {
    const int cur = kv & 1;
    if (kv < 15) {
      const size_t ko = (size_t)(kv + 1) * 64;
#pragma unroll
      for (int p = 0; p < 4; ++p) {
        const int s = tid + 128 * p;
        load_lds16(kb + (ko + sr[p]) * 64 + sc[p] * 8, (u16*)Kl[cur ^ 1] + s * 8);
        load_lds16(vb + (size_t)sr[p] * 1024 + ko + sc[p] * 8,
                   (u16*)Vl[cur ^ 1] + s * 8);
      }
    }
    const u16* Kc = (const u16*)Kl[cur];
    const u16* Vc = (const u16*)Vl[cur];

    // S^T = K x Q^T : per key-block t2, lane holds S[q=l31][16 keys]
    f32x16 S[2];
#pragma unroll
    for (int t2 = 0; t2 < 2; ++t2)
#pragma unroll
      for (int r = 0; r < 16; ++r) S[t2][r] = 0.f;
    __builtin_amdgcn_s_setprio(1);
#pragma unroll
    for (int t2 = 0; t2 < 2; ++t2) {
      const int kr = t2 * 32 + l31;
      const int sw = kr & 7;
#pragma unroll
      for (int ds = 0; ds < 4; ++ds) {
        const int pos = (ds * 2 + h) ^ sw;
        u16x8 kf = *(const u16x8*)(Kc + kr * 64 + pos * 8);
        S[t2] = mfma32(kf, qf[ds], S[t2]);
      }
    }
    __builtin_amdgcn_s_setprio(0);

    // no-max softmax (|s|<=8 after q/k LN); all values lane-local
#pragma unroll
    for (int t2 = 0; t2 < 2; ++t2)
#pragma unroll
      for (int r = 0; r < 16; ++r) {
        float pv = __expf(S[t2][r] * 0.125f);
        S[t2][r] = pv;
        lacc += pv;
      }

    // PV: rebuild A-frag (lane q=l31, keys m*16 + h*8 + e) via cvt_pk + permlane
    __builtin_amdgcn_s_setprio(1);
#pragma unroll
    for (int m = 0; m < 4; ++m) {
      const int t2 = m >> 1, ro = (m & 1) * 8;
      unsigned w0 = cvtpk_bf16(S[t2][ro + 0], S[t2][ro + 1]);
      unsigned w2 = cvtpk_bf16(S[t2][ro + 4], S[t2][ro + 5]);
      unsigned w1 = cvtpk_bf16(S[t2][ro + 2], S[t2][ro + 3]);
      unsigned w3 = cvtpk_bf16(S[t2][ro + 6], S[t2][ro + 7]);
      plswap(w0, w2);  // w0 -> {e0,e1}, w2 -> {e4,e5}
      plswap(w1, w3);  // w1 -> {e2,e3}, w3 -> {e6,e7}
      i32x4 aw;
      aw[0] = (int)w0; aw[1] = (int)w1; aw[2] = (int)w2; aw[3] = (int)w3;
      const u16x8 pa = __builtin_bit_cast(u16x8, aw);
#pragma unroll
      for (int d2 = 0; d2 < 2; ++d2) {
        const int vr = d2 * 32 + l31;
        const int pos = (m * 2 + h) ^ (vr & 7);
        u16x8 vf = *(const u16x8*)(Vc + vr * 64 + pos * 8);
        O[d2] = mfma32(pa, vf, O[d2]);
      }
    }
    __builtin_amdgcn_s_setprio(0);
    __syncthreads();
  }

  // lane l and l^32 hold complementary key-halves of the same q-row
  lacc += __shfl_xor(lacc, 32);
  const float inv = 1.f / lacc;
  const int b = bh >> 4, hh = bh & 15;
#pragma unroll
  for (int r = 0; r < 16; ++r) {
    const int qr = (r & 3) + 8 * (r >> 2) + 4 * h;  // O row for this reg
    const float invr = __shfl(inv, qr);             // inv lives at lane q
    u8* orow = xo + (size_t)(b * 1024 + qrow0 + qr) * 1024 + hh * 64;
    orow[l31] = f2fp8(O[0][r] * invr);
    orow[32 + l31] = f2fp8(O[1][r] * invr);
  }
}

extern "C" void kernel_launch(void* const* d_in, const int* in_sizes, int n_in,
                              void* d_out, int out_size, void* d_ws, size_t ws_size,
                              hipStream_t stream) {
  (void)in_sizes; (void)n_in; (void)out_size; (void)ws_size;
  const float* x      = (const float*)d_in[0];
  const float* norm_g = (const float*)d_in[1];
  const float* norm_b = (const float*)d_in[2];
  const float* W1     = (const float*)d_in[3];
  const float* b1     = (const float*)d_in[4];
  const float* qn_g   = (const float*)d_in[5];
  const float* qn_b   = (const float*)d_in[6];
  const float* kn_g   = (const float*)d_in[7];
  const float* kn_b   = (const float*)d_in[8];
  const float* projW  = (const float*)d_in[9];
  const float* projb  = (const float*)d_in[10];
  const float* mlpW   = (const float*)d_in[11];
  const float* W2     = (const float*)d_in[12];
  const float* b2     = (const float*)d_in[13];
  const float* ls_g   = (const float*)d_in[14];

  char* ws = (char*)d_ws;
  u8*  W1t8 = (u8*)(ws + 0);           // [3840][1024]  3,932,160
  u8*  pWt8 = (u8*)(ws + 3932160);     // [1024][1024]  1,048,576
  u8*  mWt8 = (u8*)(ws + 4980736);     // [1024][768]     786,432
  u8*  W2t8 = (u8*)(ws + 5767168);     // [1024][2048]  2,097,152
  u8*  nx8  = (u8*)(ws + 7864320);     // [4096][1024]  4,194,304 (then xo8)
  u16* f1   = (u16*)(ws + 12058624);   // [4096][3840] 31,457,280 bf16 (then comb fp8)
  u16* qbuf = (u16*)(ws + 43515904);   // [64][1024][64] 8,388,608
  u16* kbuf = (u16*)(ws + 51904512);   // [64][1024][64] 8,388,608
  u16* vtb  = (u16*)(ws + 60293120);   // [64][64][1024] 8,388,608
  u8*  gel8 = (u8*)(ws + 68681728);    // [4096][768]   3,145,728

  k_pre<<<11776, 256, 0, stream>>>(W1, projW, mlpW, W2, W1t8, pWt8, mWt8, W2t8,
                                   x, norm_g, norm_b, nx8);
  k_gemm1<<<dim3(30, 32), 256, 0, stream>>>(nx8, W1t8, f1, b1);
  k_mid<<<9728, 256, 0, stream>>>(f1, qn_g, qn_b, kn_g, kn_b, qbuf, kbuf, gel8,
                                  vtb);
  k_flash<<<1024, 128, 0, stream>>>(qbuf, kbuf, vtb, nx8);
  k_gemm_pm<<<dim3(16, 64), 256, 0, stream>>>(nx8, pWt8, gel8, mWt8, (u8*)f1, projb);
  k_gemm_fin<<<dim3(8, 64), 256, 0, stream>>>((u8*)f1, W2t8, (float*)d_out, b2, x,
                                              ls_g);
}

// Round 4
// 223.401 us; speedup vs baseline: 1.0709x; 1.0241x over previous
//
#include <hip/hip_runtime.h>
#include <cstdint>
#include <cstddef>

typedef unsigned short u16;
typedef unsigned char u8;
typedef __attribute__((ext_vector_type(8))) u16 u16x8;
typedef __attribute__((ext_vector_type(8))) __bf16 bf16x8;
typedef __attribute__((ext_vector_type(4))) float f32x4;
typedef __attribute__((ext_vector_type(16))) float f32x16;
typedef __attribute__((ext_vector_type(4))) int i32x4;
typedef __attribute__((ext_vector_type(8))) int i32x8;
typedef __attribute__((ext_vector_type(2))) int i32x2;

__device__ __forceinline__ u16 f2bf(float f) {
  unsigned u = __builtin_bit_cast(unsigned, f);
  return (u16)((u + 0x7FFFu + ((u >> 16) & 1u)) >> 16);
}
__device__ __forceinline__ float bf2f(u16 h) {
  return __builtin_bit_cast(float, (unsigned)h << 16);
}
__device__ __forceinline__ u8 f2fp8(float f) {
  return (u8)(__builtin_amdgcn_cvt_pk_fp8_f32(f, 0.f, 0, false) & 0xFF);
}
__device__ __forceinline__ f32x4 mfma16(u16x8 a, u16x8 b, f32x4 c) {
  return __builtin_amdgcn_mfma_f32_16x16x32_bf16(
      __builtin_bit_cast(bf16x8, a), __builtin_bit_cast(bf16x8, b), c, 0, 0, 0);
}
__device__ __forceinline__ f32x16 mfma32(u16x8 a, u16x8 b, f32x16 c) {
  return __builtin_amdgcn_mfma_f32_32x32x16_bf16(
      __builtin_bit_cast(bf16x8, a), __builtin_bit_cast(bf16x8, b), c, 0, 0, 0);
}
__device__ __forceinline__ unsigned cvtpk_bf16(float lo, float hi) {
  unsigned r;
  asm("v_cvt_pk_bf16_f32 %0, %1, %2" : "=v"(r) : "v"(lo), "v"(hi));
  return r;
}
__device__ __forceinline__ void plswap(unsigned& a, unsigned& b) {
  i32x2 r = __builtin_amdgcn_permlane32_swap((int)a, (int)b, false, false);
  a = (unsigned)r[0];
  b = (unsigned)r[1];
}
__device__ __forceinline__ void load_lds16(const void* g, void* l) {
  __builtin_amdgcn_global_load_lds(
      (const __attribute__((address_space(1))) void*)g,
      (__attribute__((address_space(3))) void*)l, 16, 0, 0);
}

// ---------------- fused pre-pass: 4 weight transposes (fp8) + x LayerNorm (fp8)
__global__ __launch_bounds__(256) void k_pre(
    const float* __restrict__ W1, const float* __restrict__ projW,
    const float* __restrict__ mlpW, const float* __restrict__ W2,
    u8* __restrict__ W1t, u8* __restrict__ pWt, u8* __restrict__ mWt,
    u8* __restrict__ W2t, const float* __restrict__ x,
    const float* __restrict__ g, const float* __restrict__ b,
    u8* __restrict__ nx8) {
  __shared__ float t[32][33];
  __shared__ float red[8];
  const int L = blockIdx.x;
  const int tid = threadIdx.x;
  if (L < 7680) {
    const float* src;
    u8* dst;
    int R, C, dR, dC, bx, by;
    if (L < 3840) {
      src = W1; dst = W1t; R = 1024; C = 3788; dR = 1024; dC = 3840;
      bx = L % 120; by = L / 120;
    } else if (L < 4864) {
      int tq = L - 3840;
      src = projW; dst = pWt; R = 1024; C = 1024; dR = 1024; dC = 1024;
      bx = tq & 31; by = tq >> 5;
    } else if (L < 5632) {
      int tq = L - 4864;
      src = mlpW; dst = mWt; R = 716; C = 1024; dR = 768; dC = 1024;
      bx = tq & 31; by = tq >> 5;
    } else {
      int tq = L - 5632;
      src = W2; dst = W2t; R = 2048; C = 1024; dR = 2048; dC = 1024;
      bx = tq & 31; by = tq >> 5;
    }
    const int n0 = bx * 32, k0 = by * 32;
    const int tx = tid & 31, ty = tid >> 5;
#pragma unroll
    for (int j = 0; j < 4; ++j) {
      int kk = k0 + ty + 8 * j, nn = n0 + tx;
      float v = (kk < R && nn < C) ? src[(size_t)kk * C + nn] : 0.f;
      t[ty + 8 * j][tx] = v;
    }
    __syncthreads();
#pragma unroll
    for (int j = 0; j < 4; ++j) {
      int nn = n0 + ty + 8 * j, kk = k0 + tx;
      if (nn < dC && kk < dR) dst[(size_t)nn * dR + kk] = f2fp8(t[tx][ty + 8 * j]);
    }
  } else {
    const int row = L - 7680;
    float4 v = ((const float4*)(x + (size_t)row * 1024))[tid];
    float s = v.x + v.y + v.z + v.w;
    float ss = v.x * v.x + v.y * v.y + v.z * v.z + v.w * v.w;
#pragma unroll
    for (int off = 1; off < 64; off <<= 1) {
      s += __shfl_xor(s, off);
      ss += __shfl_xor(ss, off);
    }
    const int wid = tid >> 6, lane = tid & 63;
    if (lane == 0) { red[wid] = s; red[4 + wid] = ss; }
    __syncthreads();
    s = red[0] + red[1] + red[2] + red[3];
    ss = red[4] + red[5] + red[6] + red[7];
    const float mean = s * (1.f / 1024.f);
    const float var = ss * (1.f / 1024.f) - mean * mean;
    const float rstd = rsqrtf(var + 1e-5f);
    float4 gv = ((const float4*)g)[tid];
    float4 bv = ((const float4*)b)[tid];
    float y0 = (v.x - mean) * rstd * gv.x + bv.x;
    float y1 = (v.y - mean) * rstd * gv.y + bv.y;
    float y2 = (v.z - mean) * rstd * gv.z + bv.z;
    float y3 = (v.w - mean) * rstd * gv.w + bv.w;
    int pk = __builtin_amdgcn_cvt_pk_fp8_f32(y0, y1, 0, false);
    pk = __builtin_amdgcn_cvt_pk_fp8_f32(y2, y3, pk, true);
    ((int*)(nx8 + (size_t)row * 1024))[tid] = pk;
  }
}

// ---------------- MX-fp8 GEMM core 128x128, 3-deep pipeline, counted vmcnt (T4):
// body: ds_read(buf[cur]) -> STAGE(kt+2 -> buf[cur-1]) -> MFMA -> vmcnt(4) ->
// s_barrier. The end-of-iter wait targets loads issued a FULL iteration earlier,
// so load latency is hidden under two compute phases. Never drains vmcnt to 0
// in the main loop. 4 staging loads/thread/tile.
__device__ __forceinline__ void gemm_fp8_core(const u8* __restrict__ A,
                                              const u8* __restrict__ B, int K,
                                              u8* Alds, u8* Blds,
                                              f32x16 (&acc)[2][2], int tid) {
  const int lane = tid & 63, wave = tid >> 6;
  const int h = lane >> 5, r32 = lane & 31;
  const int wrow = (wave >> 1) * 64, wcol = (wave & 1) * 64;
  const int srow0 = tid >> 2, spos = tid & 3;
  const int nk = K >> 6;
  auto STAGE = [&](int t, int bb) {
#pragma unroll
    for (int p = 0; p < 2; ++p) {
      const int row = p * 64 + srow0;
      const int c = spos ^ ((row >> 1) & 3);
      const size_t go = (size_t)row * K + (size_t)t * 64 + c * 16;
      load_lds16(A + go, Alds + bb * 8192 + (p * 256 + tid) * 16);
      load_lds16(B + go, Blds + bb * 8192 + (p * 256 + tid) * 16);
    }
  };
  STAGE(0, 0);
  STAGE(1, 1);
  asm volatile("s_waitcnt vmcnt(4)" ::: "memory");
  __builtin_amdgcn_s_barrier();
  int cur = 0;
  for (int kt = 0; kt < nk; ++kt) {
    const u8* Ac = Alds + cur * 8192;
    const u8* Bc = Blds + cur * 8192;
    i32x8 af[2], bf[2];
#pragma unroll
    for (int t = 0; t < 2; ++t) {
      {
        const int row = wrow + t * 32 + r32;
        const int sw = (row >> 1) & 3;
        i32x4 lo = *(const i32x4*)(Ac + row * 64 + ((2 * h) ^ sw) * 16);
        i32x4 hi = *(const i32x4*)(Ac + row * 64 + ((2 * h + 1) ^ sw) * 16);
        i32x8 a;
        a[0] = lo[0]; a[1] = lo[1]; a[2] = lo[2]; a[3] = lo[3];
        a[4] = hi[0]; a[5] = hi[1]; a[6] = hi[2]; a[7] = hi[3];
        af[t] = a;
      }
      {
        const int row = wcol + t * 32 + r32;
        const int sw = (row >> 1) & 3;
        i32x4 lo = *(const i32x4*)(Bc + row * 64 + ((2 * h) ^ sw) * 16);
        i32x4 hi = *(const i32x4*)(Bc + row * 64 + ((2 * h + 1) ^ sw) * 16);
        i32x8 b8;
        b8[0] = lo[0]; b8[1] = lo[1]; b8[2] = lo[2]; b8[3] = lo[3];
        b8[4] = hi[0]; b8[5] = hi[1]; b8[6] = hi[2]; b8[7] = hi[3];
        bf[t] = b8;
      }
    }
    if (kt + 2 < nk) STAGE(kt + 2, cur == 0 ? 2 : cur - 1);
#pragma unroll
    for (int i = 0; i < 2; ++i)
#pragma unroll
      for (int j = 0; j < 2; ++j)
        acc[i][j] = __builtin_amdgcn_mfma_scale_f32_32x32x64_f8f6f4(
            af[i], bf[j], acc[i][j], 0, 0, 0, 0x7F7F7F7F, 0, 0x7F7F7F7F);
    if (kt + 1 < nk) {
      if (kt + 2 < nk)
        asm volatile("s_waitcnt vmcnt(4)" ::: "memory");
      else
        asm volatile("s_waitcnt vmcnt(0)" ::: "memory");
      __builtin_amdgcn_s_barrier();
    }
    cur = (cur == 2) ? 0 : cur + 1;
  }
}

// ---------------- MX-fp8 GEMM core 64(M)x128(N), 3-deep pipeline, counted vmcnt.
// 3 staging loads/thread/tile -> steady wait vmcnt(3).
__device__ __forceinline__ void gemm_fp8_core64(const u8* __restrict__ A,
                                                const u8* __restrict__ B, int K,
                                                u8* Alds, u8* Blds,
                                                f32x16 (&acc)[2], int tid) {
  const int lane = tid & 63, wave = tid >> 6;
  const int h = lane >> 5, r32 = lane & 31;
  const int wrow = (wave >> 1) * 32, wcol = (wave & 1) * 64;
  const int nk = K >> 6;
  const int ra = tid >> 2, posa = tid & 3;
  const int ca = posa ^ ((ra >> 1) & 3);
  auto STAGE = [&](int t, int bb) {
    const size_t k0 = (size_t)t * 64;
    load_lds16(A + (size_t)ra * K + k0 + ca * 16, Alds + bb * 4096 + tid * 16);
#pragma unroll
    for (int p = 0; p < 2; ++p) {
      const int s = tid + 256 * p;
      const int r = s >> 2, pos = s & 3;
      const int c = pos ^ ((r >> 1) & 3);
      load_lds16(B + (size_t)r * K + k0 + c * 16, Blds + bb * 8192 + s * 16);
    }
  };
  STAGE(0, 0);
  STAGE(1, 1);
  asm volatile("s_waitcnt vmcnt(3)" ::: "memory");
  __builtin_amdgcn_s_barrier();
  int cur = 0;
  for (int kt = 0; kt < nk; ++kt) {
    const u8* Ac = Alds + cur * 4096;
    const u8* Bc = Blds + cur * 8192;
    i32x8 af, bf[2];
    {
      const int row = wrow + r32;
      const int sw = (row >> 1) & 3;
      i32x4 lo = *(const i32x4*)(Ac + row * 64 + ((2 * h) ^ sw) * 16);
      i32x4 hi = *(const i32x4*)(Ac + row * 64 + ((2 * h + 1) ^ sw) * 16);
      af[0] = lo[0]; af[1] = lo[1]; af[2] = lo[2]; af[3] = lo[3];
      af[4] = hi[0]; af[5] = hi[1]; af[6] = hi[2]; af[7] = hi[3];
    }
#pragma unroll
    for (int t = 0; t < 2; ++t) {
      const int row = wcol + t * 32 + r32;
      const int sw = (row >> 1) & 3;
      i32x4 lo = *(const i32x4*)(Bc + row * 64 + ((2 * h) ^ sw) * 16);
      i32x4 hi = *(const i32x4*)(Bc + row * 64 + ((2 * h + 1) ^ sw) * 16);
      i32x8 b8;
      b8[0] = lo[0]; b8[1] = lo[1]; b8[2] = lo[2]; b8[3] = lo[3];
      b8[4] = hi[0]; b8[5] = hi[1]; b8[6] = hi[2]; b8[7] = hi[3];
      bf[t] = b8;
    }
    if (kt + 2 < nk) STAGE(kt + 2, cur == 0 ? 2 : cur - 1);
#pragma unroll
    for (int j = 0; j < 2; ++j)
      acc[j] = __builtin_amdgcn_mfma_scale_f32_32x32x64_f8f6f4(
          af, bf[j], acc[j], 0, 0, 0, 0x7F7F7F7F, 0, 0x7F7F7F7F);
    if (kt + 1 < nk) {
      if (kt + 2 < nk)
        asm volatile("s_waitcnt vmcnt(3)" ::: "memory");
      else
        asm volatile("s_waitcnt vmcnt(0)" ::: "memory");
      __builtin_amdgcn_s_barrier();
    }
    cur = (cur == 2) ? 0 : cur + 1;
  }
}

// ---------------- GEMM1: f1[4096][3840] bf16 = nx8 @ W1t^T + b1
__global__ __launch_bounds__(256) void k_gemm1(const u8* __restrict__ nx8,
                                               const u8* __restrict__ W1t,
                                               u16* __restrict__ f1,
                                               const float* __restrict__ b1) {
  __shared__ __align__(16) u8 Alds[3 * 128 * 64];
  __shared__ __align__(16) u8 Blds[3 * 128 * 64];
  const int tid = threadIdx.x, bm = blockIdx.y, bn = blockIdx.x;
  f32x16 acc[2][2];
#pragma unroll
  for (int i = 0; i < 2; ++i)
#pragma unroll
    for (int j = 0; j < 2; ++j)
#pragma unroll
      for (int r = 0; r < 16; ++r) acc[i][j][r] = 0.f;
  gemm_fp8_core(nx8 + (size_t)bm * 128 * 1024, W1t + (size_t)bn * 128 * 1024, 1024,
                Alds, Blds, acc, tid);
  const int lane = tid & 63, wave = tid >> 6;
  const int h = lane >> 5, r32 = lane & 31;
  const int wrow = (wave >> 1) * 64, wcol = (wave & 1) * 64;
#pragma unroll
  for (int i = 0; i < 2; ++i)
#pragma unroll
    for (int j = 0; j < 2; ++j) {
      const int col = bn * 128 + wcol + j * 32 + r32;
      const float bs = (col < 3788) ? b1[col] : 0.f;
#pragma unroll
      for (int r = 0; r < 16; ++r) {
        const int row = bm * 128 + wrow + i * 32 + 4 * h + (r & 3) + 8 * (r >> 2);
        f1[(size_t)row * 3840 + col] = f2bf(acc[i][j][r] + bs);
      }
    }
}

// ---------------- proj + mlp fused (64-row tiles): comb[4096][2048] fp8
__global__ __launch_bounds__(256) void k_gemm_pm(
    const u8* __restrict__ xo, const u8* __restrict__ pWt,
    const u8* __restrict__ gel, const u8* __restrict__ mWt,
    u8* __restrict__ comb, const float* __restrict__ projb) {
  __shared__ __align__(16) u8 Alds[3 * 64 * 64];
  __shared__ __align__(16) u8 Blds[3 * 128 * 64];
  const int tid = threadIdx.x, bm = blockIdx.y, bnq = blockIdx.x;
  const u8* A;
  const u8* B;
  int K, colbase;
  const float* bias;
  if (bnq < 8) {
    A = xo + (size_t)bm * 64 * 1024;
    B = pWt + (size_t)bnq * 128 * 1024;
    K = 1024; colbase = bnq * 128; bias = projb;
  } else {
    A = gel + (size_t)bm * 64 * 768;
    B = mWt + (size_t)(bnq - 8) * 128 * 768;
    K = 768; colbase = 1024 + (bnq - 8) * 128; bias = nullptr;
  }
  f32x16 acc[2];
#pragma unroll
  for (int j = 0; j < 2; ++j)
#pragma unroll
    for (int r = 0; r < 16; ++r) acc[j][r] = 0.f;
  gemm_fp8_core64(A, B, K, Alds, Blds, acc, tid);
  const int lane = tid & 63, wave = tid >> 6;
  const int h = lane >> 5, r32 = lane & 31;
  const int wrow = (wave >> 1) * 32, wcol = (wave & 1) * 64;
#pragma unroll
  for (int j = 0; j < 2; ++j) {
    const int col = colbase + wcol + j * 32 + r32;
    const float bs = (bias != nullptr) ? bias[col] : 0.f;
#pragma unroll
    for (int r = 0; r < 16; ++r) {
      const int row = bm * 64 + wrow + 4 * h + (r & 3) + 8 * (r >> 2);
      comb[(size_t)row * 2048 + col] = f2fp8(acc[j][r] + bs);
    }
  }
}

// ---------------- final (64-row tiles): out = x + (comb @ W2t^T + b2) * ls_g
__global__ __launch_bounds__(256) void k_gemm_fin(const u8* __restrict__ comb,
                                                  const u8* __restrict__ W2t,
                                                  float* __restrict__ out,
                                                  const float* __restrict__ b2,
                                                  const float* __restrict__ x,
                                                  const float* __restrict__ lsg) {
  __shared__ __align__(16) u8 Alds[3 * 64 * 64];
  __shared__ __align__(16) u8 Blds[3 * 128 * 64];
  const int tid = threadIdx.x, bm = blockIdx.y, bn = blockIdx.x;
  f32x16 acc[2];
#pragma unroll
  for (int j = 0; j < 2; ++j)
#pragma unroll
    for (int r = 0; r < 16; ++r) acc[j][r] = 0.f;
  gemm_fp8_core64(comb + (size_t)bm * 64 * 2048, W2t + (size_t)bn * 128 * 2048, 2048,
                  Alds, Blds, acc, tid);
  const int lane = tid & 63, wave = tid >> 6;
  const int h = lane >> 5, r32 = lane & 31;
  const int wrow = (wave >> 1) * 32, wcol = (wave & 1) * 64;
#pragma unroll
  for (int j = 0; j < 2; ++j) {
    const int col = bn * 128 + wcol + j * 32 + r32;
    const float bs = b2[col], ls = lsg[col];
#pragma unroll
    for (int r = 0; r < 16; ++r) {
      const int row = bm * 64 + wrow + 4 * h + (r & 3) + 8 * (r >> 2);
      out[(size_t)row * 1024 + col] =
          x[(size_t)row * 1024 + col] + (acc[j][r] + bs) * ls;
    }
  }
}

// ---------------- fused mid-pass: q/k per-head LN + gelu, plus V^T extraction.
__global__ __launch_bounds__(256) void k_mid(const u16* __restrict__ f1,
                                             const float* __restrict__ qg,
                                             const float* __restrict__ qbb,
                                             const float* __restrict__ kg,
                                             const float* __restrict__ kbb,
                                             u16* __restrict__ q,
                                             u16* __restrict__ k,
                                             u8* __restrict__ gel,
                                             u16* __restrict__ vtb) {
  __shared__ u16 tt[32][33];
  const int tid = threadIdx.x;
  const int L = blockIdx.x;
  if (L < 4096) {
    const int row = L;
    const int rem = tid >> 3;
    const int which = rem >> 4, h = rem & 15;
    const int e8 = (tid & 7) * 8;
    u16x8 xv = *(const u16x8*)(f1 + (size_t)row * 3840 + which * 1024 + h * 64 + e8);
    float xf[8];
    float s1 = 0.f, s2 = 0.f;
#pragma unroll
    for (int e = 0; e < 8; ++e) {
      xf[e] = bf2f(xv[e]);
      s1 += xf[e];
      s2 += xf[e] * xf[e];
    }
#pragma unroll
    for (int off = 1; off < 8; off <<= 1) {
      s1 += __shfl_xor(s1, off);
      s2 += __shfl_xor(s2, off);
    }
    const float mean = s1 * (1.f / 64.f);
    const float var = s2 * (1.f / 64.f) - mean * mean;
    const float rstd = rsqrtf(var + 1e-5f);
    const float* g = (which == 0) ? qg : kg;
    const float* bb = (which == 0) ? qbb : kbb;
    float4 g0 = ((const float4*)g)[e8 >> 2], g1 = ((const float4*)g)[(e8 >> 2) + 1];
    float4 b0 = ((const float4*)bb)[e8 >> 2], b1 = ((const float4*)bb)[(e8 >> 2) + 1];
    float gv[8] = {g0.x, g0.y, g0.z, g0.w, g1.x, g1.y, g1.z, g1.w};
    float bv[8] = {b0.x, b0.y, b0.z, b0.w, b1.x, b1.y, b1.z, b1.w};
    u16x8 o;
#pragma unroll
    for (int e = 0; e < 8; ++e) o[e] = f2bf((xf[e] - mean) * rstd * gv[e] + bv[e]);
    const int b = row >> 10, n = row & 1023;
    u16* dst = (which == 0) ? q : k;
    *(u16x8*)(dst + ((size_t)(b * 16 + h) * 1024 + n) * 64 + e8) = o;
  } else if (L < 5632) {
    const int id = (L - 4096) * 256 + tid;
    const int row = id / 96, c8 = id - row * 96;
    u16x8 xv = *(const u16x8*)(f1 + (size_t)row * 3840 + 3072 + c8 * 8);
    float rr[8];
#pragma unroll
    for (int e = 0; e < 8; ++e) {
      const int col = c8 * 8 + e;
      rr[e] = 0.f;
      if (col < 716) {
        float xx = bf2f(xv[e]);
        rr[e] = 0.5f * xx * (1.f + erff(xx * 0.70710678118654752f));
      }
    }
    int p0 = __builtin_amdgcn_cvt_pk_fp8_f32(rr[0], rr[1], 0, false);
    p0 = __builtin_amdgcn_cvt_pk_fp8_f32(rr[2], rr[3], p0, true);
    int p1 = __builtin_amdgcn_cvt_pk_fp8_f32(rr[4], rr[5], 0, false);
    p1 = __builtin_amdgcn_cvt_pk_fp8_f32(rr[6], rr[7], p1, true);
    uint2 pk;
    pk.x = (unsigned)p0;
    pk.y = (unsigned)p1;
    *(uint2*)(gel + (size_t)row * 768 + c8 * 8) = pk;
  } else {
    const int t = L - 5632;
    const int xq = t & 1, yq = (t >> 1) & 31, z = t >> 6;
    const int b = z >> 4, h = z & 15;
    const int d0 = xq * 32, n0 = yq * 32;
    const int tx = tid & 31, ty = tid >> 5;
#pragma unroll
    for (int j = 0; j < 4; ++j)
      tt[ty + 8 * j][tx] =
          f1[(size_t)(b * 1024 + n0 + ty + 8 * j) * 3840 + 2048 + h * 64 + d0 + tx];
    __syncthreads();
#pragma unroll
    for (int j = 0; j < 4; ++j)
      vtb[(size_t)z * 65536 + (size_t)(d0 + ty + 8 * j) * 1024 + n0 + tx] =
          tt[tx][ty + 8 * j];
  }
}

// ---------------- flash attention v4: 128 threads = 2 waves x 32 q-rows, grid 1024.
__global__ __launch_bounds__(128) void k_flash(const u16* __restrict__ q,
                                               const u16* __restrict__ k,
                                               const u16* __restrict__ vt,
                                               u8* __restrict__ xo) {
  __shared__ __align__(16) u16 Kl[2][64 * 64];
  __shared__ __align__(16) u16 Vl[2][64 * 64];
  const int tid = threadIdx.x, wave = tid >> 6, lane = tid & 63;
  const int l31 = lane & 31, h = lane >> 5;
  const int L = blockIdx.x;
  const int xcd = L & 7, i = L >> 3;
  const int bh = xcd * 8 + (i & 7), qt = i >> 3;  // qt 0..15
  const int qrow0 = qt * 64 + wave * 32;
  const u16* qb = q + ((size_t)bh * 1024 + qrow0) * 64;
  const u16* kb = k + (size_t)bh * 1024 * 64;
  const u16* vb = vt + (size_t)bh * 64 * 1024;

  u16x8 qf[4];
#pragma unroll
  for (int ds = 0; ds < 4; ++ds)
    qf[ds] = *(const u16x8*)(qb + (size_t)l31 * 64 + ds * 16 + h * 8);

  f32x16 O[2];
#pragma unroll
  for (int d2 = 0; d2 < 2; ++d2)
#pragma unroll
    for (int r = 0; r < 16; ++r) O[d2][r] = 0.f;
  float lacc = 0.f;

  int sr[4], sc[4];
#pragma unroll
  for (int p = 0; p < 4; ++p) {
    const int s = tid + 128 * p;
    sr[p] = s >> 3;
    sc[p] = (s & 7) ^ (sr[p] & 7);
  }

#pragma unroll
  for (int p = 0; p < 4; ++p) {
    const int s = tid + 128 * p;
    load_lds16(kb + (size_t)sr[p] * 64 + sc[p] * 8, (u16*)Kl[0] + s * 8);
    load_lds16(vb + (size_t)sr[p] * 1024 + sc[p] * 8, (u16*)Vl[0] + s * 8);
  }
  __syncthreads();

  for (int kv = 0; kv < 16; ++kv) {
    const int cur = kv & 1;
    if (kv < 15) {
      const size_t ko = (size_t)(kv + 1) * 64;
#pragma unroll
      for (int p = 0; p < 4; ++p) {
        const int s = tid + 128 * p;
        load_lds16(kb + (ko + sr[p]) * 64 + sc[p] * 8, (u16*)Kl[cur ^ 1] + s * 8);
        load_lds16(vb + (size_t)sr[p] * 1024 + ko + sc[p] * 8,
                   (u16*)Vl[cur ^ 1] + s * 8);
      }
    }
    const u16* Kc = (const u16*)Kl[cur];
    const u16* Vc = (const u16*)Vl[cur];

    f32x16 S[2];
#pragma unroll
    for (int t2 = 0; t2 < 2; ++t2)
#pragma unroll
      for (int r = 0; r < 16; ++r) S[t2][r] = 0.f;
    __builtin_amdgcn_s_setprio(1);
#pragma unroll
    for (int t2 = 0; t2 < 2; ++t2) {
      const int kr = t2 * 32 + l31;
      const int sw = kr & 7;
#pragma unroll
      for (int ds = 0; ds < 4; ++ds) {
        const int pos = (ds * 2 + h) ^ sw;
        u16x8 kf = *(const u16x8*)(Kc + kr * 64 + pos * 8);
        S[t2] = mfma32(kf, qf[ds], S[t2]);
      }
    }
    __builtin_amdgcn_s_setprio(0);

#pragma unroll
    for (int t2 = 0; t2 < 2; ++t2)
#pragma unroll
      for (int r = 0; r < 16; ++r) {
        float pv = __expf(S[t2][r] * 0.125f);
        S[t2][r] = pv;
        lacc += pv;
      }

    __builtin_amdgcn_s_setprio(1);
#pragma unroll
    for (int m = 0; m < 4; ++m) {
      const int t2 = m >> 1, ro = (m & 1) * 8;
      unsigned w0 = cvtpk_bf16(S[t2][ro + 0], S[t2][ro + 1]);
      unsigned w2 = cvtpk_bf16(S[t2][ro + 4], S[t2][ro + 5]);
      unsigned w1 = cvtpk_bf16(S[t2][ro + 2], S[t2][ro + 3]);
      unsigned w3 = cvtpk_bf16(S[t2][ro + 6], S[t2][ro + 7]);
      plswap(w0, w2);
      plswap(w1, w3);
      i32x4 aw;
      aw[0] = (int)w0; aw[1] = (int)w1; aw[2] = (int)w2; aw[3] = (int)w3;
      const u16x8 pa = __builtin_bit_cast(u16x8, aw);
#pragma unroll
      for (int d2 = 0; d2 < 2; ++d2) {
        const int vr = d2 * 32 + l31;
        const int pos = (m * 2 + h) ^ (vr & 7);
        u16x8 vf = *(const u16x8*)(Vc + vr * 64 + pos * 8);
        O[d2] = mfma32(pa, vf, O[d2]);
      }
    }
    __builtin_amdgcn_s_setprio(0);
    __syncthreads();
  }

  lacc += __shfl_xor(lacc, 32);
  const float inv = 1.f / lacc;
  const int b = bh >> 4, hh = bh & 15;
#pragma unroll
  for (int r = 0; r < 16; ++r) {
    const int qr = (r & 3) + 8 * (r >> 2) + 4 * h;
    const float invr = __shfl(inv, qr);
    u8* orow = xo + (size_t)(b * 1024 + qrow0 + qr) * 1024 + hh * 64;
    orow[l31] = f2fp8(O[0][r] * invr);
    orow[32 + l31] = f2fp8(O[1][r] * invr);
  }
}

extern "C" void kernel_launch(void* const* d_in, const int* in_sizes, int n_in,
                              void* d_out, int out_size, void* d_ws, size_t ws_size,
                              hipStream_t stream) {
  (void)in_sizes; (void)n_in; (void)out_size; (void)ws_size;
  const float* x      = (const float*)d_in[0];
  const float* norm_g = (const float*)d_in[1];
  const float* norm_b = (const float*)d_in[2];
  const float* W1     = (const float*)d_in[3];
  const float* b1     = (const float*)d_in[4];
  const float* qn_g   = (const float*)d_in[5];
  const float* qn_b   = (const float*)d_in[6];
  const float* kn_g   = (const float*)d_in[7];
  const float* kn_b   = (const float*)d_in[8];
  const float* projW  = (const float*)d_in[9];
  const float* projb  = (const float*)d_in[10];
  const float* mlpW   = (const float*)d_in[11];
  const float* W2     = (const float*)d_in[12];
  const float* b2     = (const float*)d_in[13];
  const float* ls_g   = (const float*)d_in[14];

  char* ws = (char*)d_ws;
  u8*  W1t8 = (u8*)(ws + 0);           // [3840][1024]  3,932,160
  u8*  pWt8 = (u8*)(ws + 3932160);     // [1024][1024]  1,048,576
  u8*  mWt8 = (u8*)(ws + 4980736);     // [1024][768]     786,432
  u8*  W2t8 = (u8*)(ws + 5767168);     // [1024][2048]  2,097,152
  u8*  nx8  = (u8*)(ws + 7864320);     // [4096][1024]  4,194,304 (then xo8)
  u16* f1   = (u16*)(ws + 12058624);   // [4096][3840] 31,457,280 bf16 (then comb fp8)
  u16* qbuf = (u16*)(ws + 43515904);   // [64][1024][64] 8,388,608
  u16* kbuf = (u16*)(ws + 51904512);   // [64][1024][64] 8,388,608
  u16* vtb  = (u16*)(ws + 60293120);   // [64][64][1024] 8,388,608
  u8*  gel8 = (u8*)(ws + 68681728);    // [4096][768]   3,145,728

  k_pre<<<11776, 256, 0, stream>>>(W1, projW, mlpW, W2, W1t8, pWt8, mWt8, W2t8,
                                   x, norm_g, norm_b, nx8);
  k_gemm1<<<dim3(30, 32), 256, 0, stream>>>(nx8, W1t8, f1, b1);
  k_mid<<<9728, 256, 0, stream>>>(f1, qn_g, qn_b, kn_g, kn_b, qbuf, kbuf, gel8,
                                  vtb);
  k_flash<<<1024, 128, 0, stream>>>(qbuf, kbuf, vtb, nx8);
  k_gemm_pm<<<dim3(16, 64), 256, 0, stream>>>(nx8, pWt8, gel8, mWt8, (u8*)f1, projb);
  k_gemm_fin<<<dim3(8, 64), 256, 0, stream>>>((u8*)f1, W2t8, (float*)d_out, b2, x,
                                              ls_g);
}